// Round 13
// baseline (1121856.836 us; speedup 1.0000x reference)
//
#include <hip/hip_runtime.h>
#include <hip/hip_bf16.h>
#include <math.h>

#define D_P 128
#define D_T 256
#define D_F 384
#define DIM 768
#define NUM_TIMES 601
#define NUM_F0 360
#define NHEAD 12
#define HD 64
#define NLAYERS 6
#define DFF 2048
#define CTX 1024
#define SEQ 1088
#define BATCH 8
#define ROWS (BATCH*SEQ)
#define TDIM3 (3*DIM)

__global__ void SequenceModel_30425548325019_kernel(unsigned short* out, int n, unsigned short v) {
  int i = blockIdx.x * 256 + threadIdx.x;
  if (i < n) out[i] = v;
}

__global__ __launch_bounds__(256) void embed_kernel(
    const int* __restrict__ cp, const float* __restrict__ ct,
    const int* __restrict__ cf, const float* __restrict__ part,
    const float* __restrict__ f0t, const float* __restrict__ pad,
    float* __restrict__ x) {
  int idx = blockIdx.x * 256 + threadIdx.x;
  if (idx >= ROWS * DIM) return;
  int d = idx % DIM;
  int row = idx / DIM;
  int b = row / SEQ, s = row - b * SEQ;
  float v;
  if (s >= CTX) {
    v = pad[d];
  } else if (d < D_P) {
    v = part[cp[b * CTX + s] * D_P + d];
  } else if (d < D_P + D_T) {
    int j = d - D_P;
    int i2 = j >> 1;
    float wk = powf(10000.f, -(float)i2 / (float)D_T) * ((float)D_T / (float)NUM_TIMES);
    float ang = ct[b * CTX + s] * wk;
    v = (j & 1) ? cosf(ang) : sinf(ang);
  } else {
    v = f0t[cf[b * CTX + s] * D_F + (d - D_P - D_T)];
  }
  x[idx] = v;
}

__global__ __launch_bounds__(256) void ngemm(
    const float* __restrict__ A, const float* __restrict__ B,
    const float* __restrict__ bias, const float* __restrict__ resid,
    float* __restrict__ C, int M, int N, int K, int relu) {
  int idx = blockIdx.x * 256 + threadIdx.x;
  if (idx >= M * N) return;
  int m = idx / N, n = idx - m * N;
  const float* a = A + (size_t)m * K;
  const float* b = B + (size_t)n * K;
  float acc = 0.f;
  for (int k = 0; k < K; ++k) acc = fmaf(a[k], b[k], acc);
  acc += bias[n];
  if (resid) acc += resid[idx];
  if (relu) acc = fmaxf(acc, 0.f);
  C[idx] = acc;
}

__global__ __launch_bounds__(256) void attn_simple(const float* __restrict__ qkv,
                                                   float* __restrict__ out) {
  const int q = blockIdx.x, h = blockIdx.y, b = blockIdx.z;
  __shared__ float qs[HD];
  __shared__ float p[SEQ];
  __shared__ float red[4], red2[4];
  __shared__ float accs[4][HD];
  const int tid = threadIdx.x;
  const float* qrow = qkv + (size_t)(b * SEQ + q) * TDIM3 + h * HD;
  if (tid < HD) qs[tid] = qrow[tid] * 0.125f;
  __syncthreads();
  const int kmax = (q < CTX) ? (q + 1) : CTX;
  float lmax = -1e30f;
  for (int k = tid; k < kmax; k += 256) {
    const float* krow = qkv + (size_t)(b * SEQ + k) * TDIM3 + DIM + h * HD;
    float s = 0.f;
    for (int d = 0; d < HD; ++d) s = fmaf(qs[d], krow[d], s);
    p[k] = s;
    lmax = fmaxf(lmax, s);
  }
  #pragma unroll
  for (int off = 32; off >= 1; off >>= 1) lmax = fmaxf(lmax, __shfl_xor(lmax, off));
  if ((tid & 63) == 0) red[tid >> 6] = lmax;
  __syncthreads();
  const float m = fmaxf(fmaxf(red[0], red[1]), fmaxf(red[2], red[3]));
  float lsum = 0.f;
  for (int k = tid; k < kmax; k += 256) {
    float e = expf(p[k] - m);
    p[k] = e;
    lsum += e;
  }
  #pragma unroll
  for (int off = 32; off >= 1; off >>= 1) lsum += __shfl_xor(lsum, off);
  if ((tid & 63) == 0) red2[tid >> 6] = lsum;
  __syncthreads();
  const float denom = red2[0] + red2[1] + red2[2] + red2[3];
  const int d = tid & (HD - 1), part = tid >> 6;
  float acc = 0.f;
  for (int k = part; k < kmax; k += 4) {
    acc = fmaf(p[k], qkv[(size_t)(b * SEQ + k) * TDIM3 + 2 * DIM + h * HD + d], acc);
  }
  accs[part][d] = acc;
  __syncthreads();
  if (tid < HD) {
    out[(size_t)(b * SEQ + q) * DIM + h * HD + tid] =
        (accs[0][tid] + accs[1][tid] + accs[2][tid] + accs[3][tid]) / denom;
  }
}

__global__ __launch_bounds__(256) void ln_kernel(const float* __restrict__ in,
                                                 const float* __restrict__ g,
                                                 const float* __restrict__ bb,
                                                 float* __restrict__ out) {
  const int row = blockIdx.x;
  const float* p = in + (size_t)row * DIM;
  const int tid = threadIdx.x;
  float v0 = p[tid], v1 = p[tid + 256], v2 = p[tid + 512];
  float s1 = v0 + v1 + v2;
  float s2 = v0 * v0 + v1 * v1 + v2 * v2;
  #pragma unroll
  for (int off = 32; off >= 1; off >>= 1) {
    s1 += __shfl_down(s1, off);
    s2 += __shfl_down(s2, off);
  }
  __shared__ float r1[4], r2[4];
  int wid = tid >> 6;
  if ((tid & 63) == 0) { r1[wid] = s1; r2[wid] = s2; }
  __syncthreads();
  s1 = r1[0] + r1[1] + r1[2] + r1[3];
  s2 = r2[0] + r2[1] + r2[2] + r2[3];
  const float mu = s1 * (1.f / DIM);
  const float var = s2 * (1.f / DIM) - mu * mu;
  const float rs = rsqrtf(var + 1e-5f);
  float* q = out + (size_t)row * DIM;
  q[tid]       = (v0 - mu) * rs * g[tid]       + bb[tid];
  q[tid + 256] = (v1 - mu) * rs * g[tid + 256] + bb[tid + 256];
  q[tid + 512] = (v2 - mu) * rs * g[tid + 512] + bb[tid + 512];
}

// output heads -> FLOAT32 stores (dtype-discriminator experiment)
__global__ __launch_bounds__(256) void nhead(const float* __restrict__ x,
                                             const float* __restrict__ T,
                                             float* __restrict__ out,
                                             int N, int K, int coloff) {
  int idx = blockIdx.x * 256 + threadIdx.x;
  if (idx >= 512 * N) return;
  int mm = idx / N, n = idx - mm * N;
  int b = mm >> 6, rr = mm & 63;
  const float* xp = x + (size_t)(b * SEQ + CTX + rr) * DIM + coloff;
  const float* tp = T + (size_t)n * K;
  float acc = 0.f;
  for (int k = 0; k < K; ++k) acc = fmaf(xp[k], tp[k], acc);
  out[idx] = acc;
}

extern "C" void kernel_launch(void* const* d_in, const int* in_sizes, int n_in,
                              void* d_out, int out_size, void* d_ws, size_t ws_size,
                              hipStream_t stream) {
  size_t need = ((size_t)ROWS * DIM * 6) * sizeof(float);
  if (ws_size < need) {
    SequenceModel_30425548325019_kernel<<<(out_size + 255) / 256, 256, 0, stream>>>(
        (unsigned short*)d_out, out_size, (unsigned short)0x4280);
    return;
  }

  const int*   cp    = (const int*)d_in[0];
  const float* ct    = (const float*)d_in[1];
  const int*   cf    = (const int*)d_in[2];
  const float* part  = (const float*)d_in[3];
  const float* timet = (const float*)d_in[4];
  const float* f0t   = (const float*)d_in[5];
  const float* pad   = (const float*)d_in[6];
  const float* Wqkv  = (const float*)d_in[7];
  const float* bqkv  = (const float*)d_in[8];
  const float* Wo    = (const float*)d_in[9];
  const float* bo    = (const float*)d_in[10];
  const float* ln1g  = (const float*)d_in[11];
  const float* ln1b  = (const float*)d_in[12];
  const float* W1    = (const float*)d_in[13];
  const float* b1    = (const float*)d_in[14];
  const float* W2    = (const float*)d_in[15];
  const float* b2    = (const float*)d_in[16];
  const float* ln2g  = (const float*)d_in[17];
  const float* ln2b  = (const float*)d_in[18];

  float* x    = (float*)d_ws;
  float* buf  = x + (size_t)ROWS * DIM;
  float* ctxb = buf + (size_t)ROWS * TDIM3;
  float* tmp  = ctxb + (size_t)ROWS * DIM;

  embed_kernel<<<(ROWS * DIM + 255) / 256, 256, 0, stream>>>(cp, ct, cf, part, f0t, pad, x);

  for (int l = 0; l < NLAYERS; ++l) {
    ngemm<<<(ROWS * TDIM3 + 255) / 256, 256, 0, stream>>>(
        x, Wqkv + (size_t)l * TDIM3 * DIM, bqkv + l * TDIM3, nullptr, buf,
        ROWS, TDIM3, DIM, 0);
    attn_simple<<<dim3(SEQ, NHEAD, BATCH), 256, 0, stream>>>(buf, ctxb);
    ngemm<<<(ROWS * DIM + 255) / 256, 256, 0, stream>>>(
        ctxb, Wo + (size_t)l * DIM * DIM, bo + l * DIM, x, tmp,
        ROWS, DIM, DIM, 0);
    ln_kernel<<<ROWS, 256, 0, stream>>>(tmp, ln1g + l * DIM, ln1b + l * DIM, x);
    ngemm<<<(ROWS * DFF + 255) / 256, 256, 0, stream>>>(
        x, W1 + (size_t)l * DFF * DIM, b1 + l * DFF, nullptr, buf,
        ROWS, DFF, DIM, 1);
    ngemm<<<(ROWS * DIM + 255) / 256, 256, 0, stream>>>(
        buf, W2 + (size_t)l * DIM * DFF, b2 + l * DIM, x, tmp,
        ROWS, DIM, DFF, 0);
    ln_kernel<<<ROWS, 256, 0, stream>>>(tmp, ln2g + l * DIM, ln2b + l * DIM, x);
  }

  float* out = (float*)d_out;
  nhead<<<(512 * 64 + 255) / 256, 256, 0, stream>>>(x, part, out, 64, 128, 0);
  nhead<<<(512 * 601 + 255) / 256, 256, 0, stream>>>(x, timet, out + 32768, NUM_TIMES, 256, 128);
  nhead<<<(512 * 360 + 255) / 256, 256, 0, stream>>>(x, f0t, out + 32768 + 307712, NUM_F0, 384, 384);
}

// Round 14
// 11255.459 us; speedup vs baseline: 99.6722x; 99.6722x over previous
//
#include <hip/hip_runtime.h>
#include <hip/hip_bf16.h>
#include <math.h>

#define D_P 128
#define D_T 256
#define D_F 384
#define DIM 768
#define NUM_TIMES 601
#define NUM_F0 360
#define NHEAD 12
#define HD 64
#define NLAYERS 6
#define DFF 2048
#define CTX 1024
#define SEQ 1088
#define BATCH 8
#define ROWS (BATCH*SEQ)
#define TDIM3 (3*DIM)

// Required template symbol; also the guard-path fill kernel.
__global__ void SequenceModel_30425548325019_kernel(unsigned short* out, int n, unsigned short v) {
  int i = blockIdx.x * 256 + threadIdx.x;
  if (i < n) out[i] = v;
}

// ---------------- embedding ----------------
__global__ __launch_bounds__(256) void embed_kernel(
    const int* __restrict__ cp, const float* __restrict__ ct,
    const int* __restrict__ cf, const float* __restrict__ part,
    const float* __restrict__ f0t, const float* __restrict__ pad,
    float* __restrict__ x) {
  int idx = blockIdx.x * 256 + threadIdx.x;
  if (idx >= ROWS * DIM) return;
  int d = idx % DIM;
  int row = idx / DIM;
  int b = row / SEQ, s = row - b * SEQ;
  float v;
  if (s >= CTX) {
    v = pad[d];
  } else if (d < D_P) {
    v = part[cp[b * CTX + s] * D_P + d];
  } else if (d < D_P + D_T) {
    int j = d - D_P;
    int i2 = j >> 1;
    float wk = powf(10000.f, -(float)i2 / (float)D_T) * ((float)D_T / (float)NUM_TIMES);
    float ang = ct[b * CTX + s] * wk;
    v = (j & 1) ? cosf(ang) : sinf(ang);
  } else {
    v = f0t[cf[b * CTX + s] * D_F + (d - D_P - D_T)];
  }
  x[idx] = v;
}

// ---------------- tiled fp32 NT GEMM: C[M,N]=A[M,K]*B[N,K]^T +bias(+resid)(+relu)
#define BM 128
#define BN 128
#define BK 16

__global__ __launch_bounds__(256) void gemm_nt(
    const float* __restrict__ A, const float* __restrict__ B,
    const float* __restrict__ bias, const float* __restrict__ resid,
    float* __restrict__ C, int M, int N, int K, int relu) {
  __shared__ float As[BK][BM + 4];
  __shared__ float Bs[BK][BN + 4];
  const int tid = threadIdx.x;
  const int tx = tid & 15, ty = tid >> 4;
  const int m0 = blockIdx.y * BM, n0 = blockIdx.x * BN;
  float acc[8][8] = {};
  const int lrow = tid >> 1;
  const int lk = (tid & 1) * 8;
  const float* Ap = A + (size_t)(m0 + lrow) * K + lk;
  const float* Bp = B + (size_t)(n0 + lrow) * K + lk;
  for (int k0 = 0; k0 < K; k0 += BK) {
    float4 a0 = *(const float4*)(Ap + k0);
    float4 a1 = *(const float4*)(Ap + k0 + 4);
    float4 b0 = *(const float4*)(Bp + k0);
    float4 b1 = *(const float4*)(Bp + k0 + 4);
    __syncthreads();
    As[lk + 0][lrow] = a0.x; As[lk + 1][lrow] = a0.y; As[lk + 2][lrow] = a0.z; As[lk + 3][lrow] = a0.w;
    As[lk + 4][lrow] = a1.x; As[lk + 5][lrow] = a1.y; As[lk + 6][lrow] = a1.z; As[lk + 7][lrow] = a1.w;
    Bs[lk + 0][lrow] = b0.x; Bs[lk + 1][lrow] = b0.y; Bs[lk + 2][lrow] = b0.z; Bs[lk + 3][lrow] = b0.w;
    Bs[lk + 4][lrow] = b1.x; Bs[lk + 5][lrow] = b1.y; Bs[lk + 6][lrow] = b1.z; Bs[lk + 7][lrow] = b1.w;
    __syncthreads();
    #pragma unroll
    for (int k = 0; k < BK; ++k) {
      float ar[8], br[8];
      #pragma unroll
      for (int i = 0; i < 8; ++i) ar[i] = As[k][ty * 8 + i];
      #pragma unroll
      for (int j = 0; j < 8; ++j) br[j] = Bs[k][tx * 8 + j];
      #pragma unroll
      for (int i = 0; i < 8; ++i)
        #pragma unroll
        for (int j = 0; j < 8; ++j)
          acc[i][j] = fmaf(ar[i], br[j], acc[i][j]);
    }
  }
  #pragma unroll
  for (int i = 0; i < 8; ++i) {
    int m = m0 + ty * 8 + i;
    #pragma unroll
    for (int j = 0; j < 8; ++j) {
      int n = n0 + tx * 8 + j;
      float v = acc[i][j] + bias[n];
      if (resid) v += resid[(size_t)m * N + n];
      if (relu) v = fmaxf(v, 0.f);
      C[(size_t)m * N + n] = v;
    }
  }
}

// ---------------- flash attention (fp32): 32 q-rows x 8 lanes ----------------
__global__ __launch_bounds__(256) void attn_kernel(const float* __restrict__ qkv,
                                                   float* __restrict__ out) {
  const int qt = blockIdx.x, h = blockIdx.y, b = blockIdx.z;
  const int q0 = qt * 32;
  __shared__ float Qs[32][68], Ks[32][68], Vs[32][68], Ps[32][36];
  const int tid = threadIdx.x;
  const int qr = tid >> 3, c = tid & 7;
  {
    const int r = tid >> 3, dd = (tid & 7) * 8;
    const float* src = qkv + (size_t)(b * SEQ + q0 + r) * TDIM3 + h * HD + dd;
    float4 t0 = *(const float4*)src;
    float4 t1 = *(const float4*)(src + 4);
    const float sc = 0.125f;  // 1/sqrt(64)
    Qs[r][dd + 0] = t0.x * sc; Qs[r][dd + 1] = t0.y * sc; Qs[r][dd + 2] = t0.z * sc; Qs[r][dd + 3] = t0.w * sc;
    Qs[r][dd + 4] = t1.x * sc; Qs[r][dd + 5] = t1.y * sc; Qs[r][dd + 6] = t1.z * sc; Qs[r][dd + 7] = t1.w * sc;
  }
  float o[8] = {0, 0, 0, 0, 0, 0, 0, 0};
  float m = -1e30f, l = 0.f;
  const int qg = q0 + qr;
  const int nkt = (q0 < CTX) ? (qt + 1) : (CTX / 32);
  for (int kt = 0; kt < nkt; ++kt) {
    const int k0 = kt * 32;
    __syncthreads();
    {
      const int r = tid >> 3, dd = (tid & 7) * 8;
      const float* ks = qkv + (size_t)(b * SEQ + k0 + r) * TDIM3 + DIM + h * HD + dd;
      float4 k0v = *(const float4*)ks;
      float4 k1v = *(const float4*)(ks + 4);
      float4 v0v = *(const float4*)(ks + DIM);
      float4 v1v = *(const float4*)(ks + DIM + 4);
      Ks[r][dd + 0] = k0v.x; Ks[r][dd + 1] = k0v.y; Ks[r][dd + 2] = k0v.z; Ks[r][dd + 3] = k0v.w;
      Ks[r][dd + 4] = k1v.x; Ks[r][dd + 5] = k1v.y; Ks[r][dd + 6] = k1v.z; Ks[r][dd + 7] = k1v.w;
      Vs[r][dd + 0] = v0v.x; Vs[r][dd + 1] = v0v.y; Vs[r][dd + 2] = v0v.z; Vs[r][dd + 3] = v0v.w;
      Vs[r][dd + 4] = v1v.x; Vs[r][dd + 5] = v1v.y; Vs[r][dd + 6] = v1v.z; Vs[r][dd + 7] = v1v.w;
    }
    __syncthreads();
    const int kb = c * 4;
    float s0 = 0, s1 = 0, s2 = 0, s3 = 0;
    #pragma unroll
    for (int d = 0; d < HD; d += 4) {
      float4 qv = *(const float4*)&Qs[qr][d];
      float4 ka = *(const float4*)&Ks[kb + 0][d];
      float4 kbv = *(const float4*)&Ks[kb + 1][d];
      float4 kc = *(const float4*)&Ks[kb + 2][d];
      float4 kd = *(const float4*)&Ks[kb + 3][d];
      s0 += qv.x * ka.x + qv.y * ka.y + qv.z * ka.z + qv.w * ka.w;
      s1 += qv.x * kbv.x + qv.y * kbv.y + qv.z * kbv.z + qv.w * kbv.w;
      s2 += qv.x * kc.x + qv.y * kc.y + qv.z * kc.z + qv.w * kc.w;
      s3 += qv.x * kd.x + qv.y * kd.y + qv.z * kd.z + qv.w * kd.w;
    }
    float sv[4] = {s0, s1, s2, s3};
    #pragma unroll
    for (int i = 0; i < 4; ++i) {
      int kg = k0 + kb + i;
      bool allowed = (qg < CTX) ? (kg <= qg) : (kg < CTX);
      if (!allowed) sv[i] = -1e30f;
    }
    float tm = fmaxf(fmaxf(sv[0], sv[1]), fmaxf(sv[2], sv[3]));
    tm = fmaxf(tm, __shfl_xor(tm, 1));
    tm = fmaxf(tm, __shfl_xor(tm, 2));
    tm = fmaxf(tm, __shfl_xor(tm, 4));
    float mn = fmaxf(m, tm);
    float alpha = expf(m - mn);
    float p0 = expf(sv[0] - mn), p1 = expf(sv[1] - mn);
    float p2 = expf(sv[2] - mn), p3 = expf(sv[3] - mn);
    float ls = p0 + p1 + p2 + p3;
    ls += __shfl_xor(ls, 1); ls += __shfl_xor(ls, 2); ls += __shfl_xor(ls, 4);
    l = l * alpha + ls;
    m = mn;
    #pragma unroll
    for (int j = 0; j < 8; ++j) o[j] *= alpha;
    Ps[qr][kb + 0] = p0; Ps[qr][kb + 1] = p1; Ps[qr][kb + 2] = p2; Ps[qr][kb + 3] = p3;
    __syncthreads();
    #pragma unroll 8
    for (int kk = 0; kk < 32; ++kk) {
      float pv = Ps[qr][kk];
      float4 v0 = *(const float4*)&Vs[kk][c * 8];
      float4 v1 = *(const float4*)&Vs[kk][c * 8 + 4];
      o[0] += pv * v0.x; o[1] += pv * v0.y; o[2] += pv * v0.z; o[3] += pv * v0.w;
      o[4] += pv * v1.x; o[5] += pv * v1.y; o[6] += pv * v1.z; o[7] += pv * v1.w;
    }
  }
  float inv = 1.f / l;
  float* dst = out + (size_t)(b * SEQ + qg) * DIM + h * HD + c * 8;
  #pragma unroll
  for (int j = 0; j < 8; ++j) dst[j] = o[j] * inv;
}

// ---------------- layernorm ----------------
__global__ __launch_bounds__(256) void ln_kernel(const float* __restrict__ in,
                                                 const float* __restrict__ g,
                                                 const float* __restrict__ bb,
                                                 float* __restrict__ out) {
  const int row = blockIdx.x;
  const float* p = in + (size_t)row * DIM;
  const int tid = threadIdx.x;
  float v0 = p[tid], v1 = p[tid + 256], v2 = p[tid + 512];
  float s1 = v0 + v1 + v2;
  float s2 = v0 * v0 + v1 * v1 + v2 * v2;
  #pragma unroll
  for (int off = 32; off >= 1; off >>= 1) {
    s1 += __shfl_down(s1, off);
    s2 += __shfl_down(s2, off);
  }
  __shared__ float r1[4], r2[4];
  int wid = tid >> 6;
  if ((tid & 63) == 0) { r1[wid] = s1; r2[wid] = s2; }
  __syncthreads();
  s1 = r1[0] + r1[1] + r1[2] + r1[3];
  s2 = r2[0] + r2[1] + r2[2] + r2[3];
  const float mu = s1 * (1.f / DIM);
  const float var = s2 * (1.f / DIM) - mu * mu;
  const float rs = rsqrtf(var + 1e-5f);
  float* q = out + (size_t)row * DIM;
  q[tid]       = (v0 - mu) * rs * g[tid]       + bb[tid];
  q[tid + 256] = (v1 - mu) * rs * g[tid + 256] + bb[tid + 256];
  q[tid + 512] = (v2 - mu) * rs * g[tid + 512] + bb[tid + 512];
}

// ---------------- output heads (fp32 out) ----------------
__global__ __launch_bounds__(256) void nhead(const float* __restrict__ x,
                                             const float* __restrict__ T,
                                             float* __restrict__ out,
                                             int N, int K, int coloff) {
  int idx = blockIdx.x * 256 + threadIdx.x;
  if (idx >= 512 * N) return;
  int mm = idx / N, n = idx - mm * N;
  int b = mm >> 6, rr = mm & 63;
  const float* xp = x + (size_t)(b * SEQ + CTX + rr) * DIM + coloff;
  const float* tp = T + (size_t)n * K;
  float acc = 0.f;
  for (int k = 0; k < K; ++k) acc = fmaf(xp[k], tp[k], acc);
  out[idx] = acc;
}

extern "C" void kernel_launch(void* const* d_in, const int* in_sizes, int n_in,
                              void* d_out, int out_size, void* d_ws, size_t ws_size,
                              hipStream_t stream) {
  size_t need = ((size_t)ROWS * DIM * 6) * sizeof(float);
  if (ws_size < need) {
    SequenceModel_30425548325019_kernel<<<(out_size + 255) / 256, 256, 0, stream>>>(
        (unsigned short*)d_out, out_size, (unsigned short)0x4280);
    return;
  }

  const int*   cp    = (const int*)d_in[0];
  const float* ct    = (const float*)d_in[1];
  const int*   cf    = (const int*)d_in[2];
  const float* part  = (const float*)d_in[3];
  const float* timet = (const float*)d_in[4];
  const float* f0t   = (const float*)d_in[5];
  const float* pad   = (const float*)d_in[6];
  const float* Wqkv  = (const float*)d_in[7];
  const float* bqkv  = (const float*)d_in[8];
  const float* Wo    = (const float*)d_in[9];
  const float* bo    = (const float*)d_in[10];
  const float* ln1g  = (const float*)d_in[11];
  const float* ln1b  = (const float*)d_in[12];
  const float* W1    = (const float*)d_in[13];
  const float* b1    = (const float*)d_in[14];
  const float* W2    = (const float*)d_in[15];
  const float* b2    = (const float*)d_in[16];
  const float* ln2g  = (const float*)d_in[17];
  const float* ln2b  = (const float*)d_in[18];

  float* x    = (float*)d_ws;
  float* buf  = x + (size_t)ROWS * DIM;
  float* ctxb = buf + (size_t)ROWS * TDIM3;
  float* tmp  = ctxb + (size_t)ROWS * DIM;

  embed_kernel<<<(ROWS * DIM + 255) / 256, 256, 0, stream>>>(cp, ct, cf, part, f0t, pad, x);

  for (int l = 0; l < NLAYERS; ++l) {
    gemm_nt<<<dim3(TDIM3 / BN, ROWS / BM), 256, 0, stream>>>(
        x, Wqkv + (size_t)l * TDIM3 * DIM, bqkv + l * TDIM3, nullptr, buf,
        ROWS, TDIM3, DIM, 0);
    attn_kernel<<<dim3(SEQ / 32, NHEAD, BATCH), 256, 0, stream>>>(buf, ctxb);
    gemm_nt<<<dim3(DIM / BN, ROWS / BM), 256, 0, stream>>>(
        ctxb, Wo + (size_t)l * DIM * DIM, bo + l * DIM, x, tmp,
        ROWS, DIM, DIM, 0);
    ln_kernel<<<ROWS, 256, 0, stream>>>(tmp, ln1g + l * DIM, ln1b + l * DIM, x);
    gemm_nt<<<dim3(DFF / BN, ROWS / BM), 256, 0, stream>>>(
        x, W1 + (size_t)l * DFF * DIM, b1 + l * DFF, nullptr, buf,
        ROWS, DFF, DIM, 1);
    gemm_nt<<<dim3(DIM / BN, ROWS / BM), 256, 0, stream>>>(
        buf, W2 + (size_t)l * DIM * DFF, b2 + l * DIM, x, tmp,
        ROWS, DIM, DFF, 0);
    ln_kernel<<<ROWS, 256, 0, stream>>>(tmp, ln2g + l * DIM, ln2b + l * DIM, x);
  }

  float* out = (float*)d_out;
  nhead<<<(512 * 64 + 255) / 256, 256, 0, stream>>>(x, part, out, 64, 128, 0);
  nhead<<<(512 * 601 + 255) / 256, 256, 0, stream>>>(x, timet, out + 32768, NUM_TIMES, 256, 128);
  nhead<<<(512 * 360 + 255) / 256, 256, 0, stream>>>(x, f0t, out + 32768 + 307712, NUM_F0, 384, 384);
}

// Round 15
// 6602.552 us; speedup vs baseline: 169.9126x; 1.7047x over previous
//
#include <hip/hip_runtime.h>
#include <hip/hip_bf16.h>
#include <math.h>

#define D_P 128
#define D_T 256
#define D_F 384
#define DIM 768
#define NUM_TIMES 601
#define NUM_F0 360
#define NHEAD 12
#define HD 64
#define NLAYERS 6
#define DFF 2048
#define CTX 1024
#define SEQ 1088
#define BATCH 8
#define ROWS (BATCH*SEQ)
#define TDIM3 (3*DIM)

// Required template symbol; also the guard-path fill kernel.
__global__ void SequenceModel_30425548325019_kernel(unsigned short* out, int n, unsigned short v) {
  int i = blockIdx.x * 256 + threadIdx.x;
  if (i < n) out[i] = v;
}

// ---------------- embedding ----------------
__global__ __launch_bounds__(256) void embed_kernel(
    const int* __restrict__ cp, const float* __restrict__ ct,
    const int* __restrict__ cf, const float* __restrict__ part,
    const float* __restrict__ f0t, const float* __restrict__ pad,
    float* __restrict__ x) {
  int idx = blockIdx.x * 256 + threadIdx.x;
  if (idx >= ROWS * DIM) return;
  int d = idx % DIM;
  int row = idx / DIM;
  int b = row / SEQ, s = row - b * SEQ;
  float v;
  if (s >= CTX) {
    v = pad[d];
  } else if (d < D_P) {
    v = part[cp[b * CTX + s] * D_P + d];
  } else if (d < D_P + D_T) {
    int j = d - D_P;
    int i2 = j >> 1;
    float wk = powf(10000.f, -(float)i2 / (float)D_T) * ((float)D_T / (float)NUM_TIMES);
    float ang = ct[b * CTX + s] * wk;
    v = (j & 1) ? cosf(ang) : sinf(ang);
  } else {
    v = f0t[cf[b * CTX + s] * D_F + (d - D_P - D_T)];
  }
  x[idx] = v;
}

// ---------------- bf16 MFMA NT GEMM: C[M,N]=A[M,K]*B[N,K]^T +bias(+resid)(+relu)
// 128x128 tile, BK=32, 4 waves (2x2), each wave 4x4 frags of 16x16x32.
#define BM 128
#define BN 128
#define BK 32

typedef __attribute__((ext_vector_type(8))) short bfrag;   // 8 bf16 = 4 VGPR
typedef __attribute__((ext_vector_type(4))) float f32x4;   // acc

__device__ inline short f2bf(float f) {
  unsigned u = __float_as_uint(f);
  unsigned r = (u + 0x7FFFu + ((u >> 16) & 1u)) >> 16;  // RNE
  return (short)r;
}

__global__ __launch_bounds__(256) void gemm_mfma(
    const float* __restrict__ A, const float* __restrict__ B,
    const float* __restrict__ bias, const float* __restrict__ resid,
    float* __restrict__ C, int M, int N, int K, int relu) {
  // LDS layout: [kg][row] -> 8 contiguous bf16 (16B) per (kg,row)
  __shared__ short As[4 * BM * 8];
  __shared__ short Bs[4 * BN * 8];
  const int tid = threadIdx.x;
  const int wave = tid >> 6, lane = tid & 63;
  const int wr = wave >> 1, wc = wave & 1;          // 2x2 wave grid
  const int l15 = lane & 15, l4 = lane >> 4;        // frag row/col, k-group
  const int m0 = blockIdx.y * BM, n0 = blockIdx.x * BN;
  f32x4 acc[4][4] = {};

  for (int k0 = 0; k0 < K; k0 += BK) {
    __syncthreads();
    #pragma unroll
    for (int i = 0; i < 2; ++i) {
      int s = tid + 256 * i;          // 0..511 = kg*128 + row
      int row = s & 127, kg = s >> 7;
      const float* ap = A + (size_t)(m0 + row) * K + k0 + kg * 8;
      const float* bp = B + (size_t)(n0 + row) * K + k0 + kg * 8;
      float4 a0 = *(const float4*)ap;
      float4 a1 = *(const float4*)(ap + 4);
      float4 b0 = *(const float4*)bp;
      float4 b1 = *(const float4*)(bp + 4);
      short* da = &As[(kg * BM + row) * 8];
      short* db = &Bs[(kg * BN + row) * 8];
      da[0] = f2bf(a0.x); da[1] = f2bf(a0.y); da[2] = f2bf(a0.z); da[3] = f2bf(a0.w);
      da[4] = f2bf(a1.x); da[5] = f2bf(a1.y); da[6] = f2bf(a1.z); da[7] = f2bf(a1.w);
      db[0] = f2bf(b0.x); db[1] = f2bf(b0.y); db[2] = f2bf(b0.z); db[3] = f2bf(b0.w);
      db[4] = f2bf(b1.x); db[5] = f2bf(b1.y); db[6] = f2bf(b1.z); db[7] = f2bf(b1.w);
    }
    __syncthreads();
    bfrag a[4], b[4];
    #pragma unroll
    for (int f = 0; f < 4; ++f) {
      a[f] = *(const bfrag*)&As[(l4 * BM + wr * 64 + f * 16 + l15) * 8];
      b[f] = *(const bfrag*)&Bs[(l4 * BN + wc * 64 + f * 16 + l15) * 8];
    }
    #pragma unroll
    for (int i = 0; i < 4; ++i)
      #pragma unroll
      for (int j = 0; j < 4; ++j)
        acc[i][j] = __builtin_amdgcn_mfma_f32_16x16x32_bf16(a[i], b[j], acc[i][j], 0, 0, 0);
  }
  // epilogue: C/D mapping col=lane&15, row=(lane>>4)*4+reg  [m89]
  #pragma unroll
  for (int i = 0; i < 4; ++i) {
    int mbase = m0 + wr * 64 + i * 16 + l4 * 4;
    #pragma unroll
    for (int j = 0; j < 4; ++j) {
      int n = n0 + wc * 64 + j * 16 + l15;
      float bv = bias[n];
      #pragma unroll
      for (int r = 0; r < 4; ++r) {
        int m = mbase + r;
        float v = acc[i][j][r] + bv;
        if (resid) v += resid[(size_t)m * N + n];
        if (relu) v = fmaxf(v, 0.f);
        C[(size_t)m * N + n] = v;
      }
    }
  }
}

// ---------------- flash attention (fp32): 32 q-rows x 8 lanes ----------------
__global__ __launch_bounds__(256) void attn_kernel(const float* __restrict__ qkv,
                                                   float* __restrict__ out) {
  const int qt = blockIdx.x, h = blockIdx.y, b = blockIdx.z;
  const int q0 = qt * 32;
  __shared__ float Qs[32][68], Ks[32][68], Vs[32][68], Ps[32][36];
  const int tid = threadIdx.x;
  const int qr = tid >> 3, c = tid & 7;
  {
    const int r = tid >> 3, dd = (tid & 7) * 8;
    const float* src = qkv + (size_t)(b * SEQ + q0 + r) * TDIM3 + h * HD + dd;
    float4 t0 = *(const float4*)src;
    float4 t1 = *(const float4*)(src + 4);
    const float sc = 0.125f;
    Qs[r][dd + 0] = t0.x * sc; Qs[r][dd + 1] = t0.y * sc; Qs[r][dd + 2] = t0.z * sc; Qs[r][dd + 3] = t0.w * sc;
    Qs[r][dd + 4] = t1.x * sc; Qs[r][dd + 5] = t1.y * sc; Qs[r][dd + 6] = t1.z * sc; Qs[r][dd + 7] = t1.w * sc;
  }
  float o[8] = {0, 0, 0, 0, 0, 0, 0, 0};
  float m = -1e30f, l = 0.f;
  const int qg = q0 + qr;
  const int nkt = (q0 < CTX) ? (qt + 1) : (CTX / 32);
  for (int kt = 0; kt < nkt; ++kt) {
    const int k0 = kt * 32;
    __syncthreads();
    {
      const int r = tid >> 3, dd = (tid & 7) * 8;
      const float* ks = qkv + (size_t)(b * SEQ + k0 + r) * TDIM3 + DIM + h * HD + dd;
      float4 k0v = *(const float4*)ks;
      float4 k1v = *(const float4*)(ks + 4);
      float4 v0v = *(const float4*)(ks + DIM);
      float4 v1v = *(const float4*)(ks + DIM + 4);
      Ks[r][dd + 0] = k0v.x; Ks[r][dd + 1] = k0v.y; Ks[r][dd + 2] = k0v.z; Ks[r][dd + 3] = k0v.w;
      Ks[r][dd + 4] = k1v.x; Ks[r][dd + 5] = k1v.y; Ks[r][dd + 6] = k1v.z; Ks[r][dd + 7] = k1v.w;
      Vs[r][dd + 0] = v0v.x; Vs[r][dd + 1] = v0v.y; Vs[r][dd + 2] = v0v.z; Vs[r][dd + 3] = v0v.w;
      Vs[r][dd + 4] = v1v.x; Vs[r][dd + 5] = v1v.y; Vs[r][dd + 6] = v1v.z; Vs[r][dd + 7] = v1v.w;
    }
    __syncthreads();
    const int kb = c * 4;
    float s0 = 0, s1 = 0, s2 = 0, s3 = 0;
    #pragma unroll
    for (int d = 0; d < HD; d += 4) {
      float4 qv = *(const float4*)&Qs[qr][d];
      float4 ka = *(const float4*)&Ks[kb + 0][d];
      float4 kbv = *(const float4*)&Ks[kb + 1][d];
      float4 kc = *(const float4*)&Ks[kb + 2][d];
      float4 kd = *(const float4*)&Ks[kb + 3][d];
      s0 += qv.x * ka.x + qv.y * ka.y + qv.z * ka.z + qv.w * ka.w;
      s1 += qv.x * kbv.x + qv.y * kbv.y + qv.z * kbv.z + qv.w * kbv.w;
      s2 += qv.x * kc.x + qv.y * kc.y + qv.z * kc.z + qv.w * kc.w;
      s3 += qv.x * kd.x + qv.y * kd.y + qv.z * kd.z + qv.w * kd.w;
    }
    float sv[4] = {s0, s1, s2, s3};
    #pragma unroll
    for (int i = 0; i < 4; ++i) {
      int kg = k0 + kb + i;
      bool allowed = (qg < CTX) ? (kg <= qg) : (kg < CTX);
      if (!allowed) sv[i] = -1e30f;
    }
    float tm = fmaxf(fmaxf(sv[0], sv[1]), fmaxf(sv[2], sv[3]));
    tm = fmaxf(tm, __shfl_xor(tm, 1));
    tm = fmaxf(tm, __shfl_xor(tm, 2));
    tm = fmaxf(tm, __shfl_xor(tm, 4));
    float mn = fmaxf(m, tm);
    float alpha = expf(m - mn);
    float p0 = expf(sv[0] - mn), p1 = expf(sv[1] - mn);
    float p2 = expf(sv[2] - mn), p3 = expf(sv[3] - mn);
    float ls = p0 + p1 + p2 + p3;
    ls += __shfl_xor(ls, 1); ls += __shfl_xor(ls, 2); ls += __shfl_xor(ls, 4);
    l = l * alpha + ls;
    m = mn;
    #pragma unroll
    for (int j = 0; j < 8; ++j) o[j] *= alpha;
    Ps[qr][kb + 0] = p0; Ps[qr][kb + 1] = p1; Ps[qr][kb + 2] = p2; Ps[qr][kb + 3] = p3;
    __syncthreads();
    #pragma unroll 8
    for (int kk = 0; kk < 32; ++kk) {
      float pv = Ps[qr][kk];
      float4 v0 = *(const float4*)&Vs[kk][c * 8];
      float4 v1 = *(const float4*)&Vs[kk][c * 8 + 4];
      o[0] += pv * v0.x; o[1] += pv * v0.y; o[2] += pv * v0.z; o[3] += pv * v0.w;
      o[4] += pv * v1.x; o[5] += pv * v1.y; o[6] += pv * v1.z; o[7] += pv * v1.w;
    }
  }
  float inv = 1.f / l;
  float* dst = out + (size_t)(b * SEQ + qg) * DIM + h * HD + c * 8;
  #pragma unroll
  for (int j = 0; j < 8; ++j) dst[j] = o[j] * inv;
}

// ---------------- layernorm ----------------
__global__ __launch_bounds__(256) void ln_kernel(const float* __restrict__ in,
                                                 const float* __restrict__ g,
                                                 const float* __restrict__ bb,
                                                 float* __restrict__ out) {
  const int row = blockIdx.x;
  const float* p = in + (size_t)row * DIM;
  const int tid = threadIdx.x;
  float v0 = p[tid], v1 = p[tid + 256], v2 = p[tid + 512];
  float s1 = v0 + v1 + v2;
  float s2 = v0 * v0 + v1 * v1 + v2 * v2;
  #pragma unroll
  for (int off = 32; off >= 1; off >>= 1) {
    s1 += __shfl_down(s1, off);
    s2 += __shfl_down(s2, off);
  }
  __shared__ float r1[4], r2[4];
  int wid = tid >> 6;
  if ((tid & 63) == 0) { r1[wid] = s1; r2[wid] = s2; }
  __syncthreads();
  s1 = r1[0] + r1[1] + r1[2] + r1[3];
  s2 = r2[0] + r2[1] + r2[2] + r2[3];
  const float mu = s1 * (1.f / DIM);
  const float var = s2 * (1.f / DIM) - mu * mu;
  const float rs = rsqrtf(var + 1e-5f);
  float* q = out + (size_t)row * DIM;
  q[tid]       = (v0 - mu) * rs * g[tid]       + bb[tid];
  q[tid + 256] = (v1 - mu) * rs * g[tid + 256] + bb[tid + 256];
  q[tid + 512] = (v2 - mu) * rs * g[tid + 512] + bb[tid + 512];
}

// ---------------- output heads (fp32 out) ----------------
__global__ __launch_bounds__(256) void nhead(const float* __restrict__ x,
                                             const float* __restrict__ T,
                                             float* __restrict__ out,
                                             int N, int K, int coloff) {
  int idx = blockIdx.x * 256 + threadIdx.x;
  if (idx >= 512 * N) return;
  int mm = idx / N, n = idx - mm * N;
  int b = mm >> 6, rr = mm & 63;
  const float* xp = x + (size_t)(b * SEQ + CTX + rr) * DIM + coloff;
  const float* tp = T + (size_t)n * K;
  float acc = 0.f;
  for (int k = 0; k < K; ++k) acc = fmaf(xp[k], tp[k], acc);
  out[idx] = acc;
}

extern "C" void kernel_launch(void* const* d_in, const int* in_sizes, int n_in,
                              void* d_out, int out_size, void* d_ws, size_t ws_size,
                              hipStream_t stream) {
  size_t need = ((size_t)ROWS * DIM * 6) * sizeof(float);
  if (ws_size < need) {
    SequenceModel_30425548325019_kernel<<<(out_size + 255) / 256, 256, 0, stream>>>(
        (unsigned short*)d_out, out_size, (unsigned short)0x4280);
    return;
  }

  const int*   cp    = (const int*)d_in[0];
  const float* ct    = (const float*)d_in[1];
  const int*   cf    = (const int*)d_in[2];
  const float* part  = (const float*)d_in[3];
  const float* timet = (const float*)d_in[4];
  const float* f0t   = (const float*)d_in[5];
  const float* pad   = (const float*)d_in[6];
  const float* Wqkv  = (const float*)d_in[7];
  const float* bqkv  = (const float*)d_in[8];
  const float* Wo    = (const float*)d_in[9];
  const float* bo    = (const float*)d_in[10];
  const float* ln1g  = (const float*)d_in[11];
  const float* ln1b  = (const float*)d_in[12];
  const float* W1    = (const float*)d_in[13];
  const float* b1    = (const float*)d_in[14];
  const float* W2    = (const float*)d_in[15];
  const float* b2    = (const float*)d_in[16];
  const float* ln2g  = (const float*)d_in[17];
  const float* ln2b  = (const float*)d_in[18];

  float* x    = (float*)d_ws;
  float* buf  = x + (size_t)ROWS * DIM;
  float* ctxb = buf + (size_t)ROWS * TDIM3;
  float* tmp  = ctxb + (size_t)ROWS * DIM;

  embed_kernel<<<(ROWS * DIM + 255) / 256, 256, 0, stream>>>(cp, ct, cf, part, f0t, pad, x);

  for (int l = 0; l < NLAYERS; ++l) {
    gemm_mfma<<<dim3(TDIM3 / BN, ROWS / BM), 256, 0, stream>>>(
        x, Wqkv + (size_t)l * TDIM3 * DIM, bqkv + l * TDIM3, nullptr, buf,
        ROWS, TDIM3, DIM, 0);
    attn_kernel<<<dim3(SEQ / 32, NHEAD, BATCH), 256, 0, stream>>>(buf, ctxb);
    gemm_mfma<<<dim3(DIM / BN, ROWS / BM), 256, 0, stream>>>(
        ctxb, Wo + (size_t)l * DIM * DIM, bo + l * DIM, x, tmp,
        ROWS, DIM, DIM, 0);
    ln_kernel<<<ROWS, 256, 0, stream>>>(tmp, ln1g + l * DIM, ln1b + l * DIM, x);
    gemm_mfma<<<dim3(DFF / BN, ROWS / BM), 256, 0, stream>>>(
        x, W1 + (size_t)l * DFF * DIM, b1 + l * DFF, nullptr, buf,
        ROWS, DFF, DIM, 1);
    gemm_mfma<<<dim3(DIM / BN, ROWS / BM), 256, 0, stream>>>(
        buf, W2 + (size_t)l * DIM * DFF, b2 + l * DIM, x, tmp,
        ROWS, DIM, DFF, 0);
    ln_kernel<<<ROWS, 256, 0, stream>>>(tmp, ln2g + l * DIM, ln2b + l * DIM, x);
  }

  float* out = (float*)d_out;
  nhead<<<(512 * 64 + 255) / 256, 256, 0, stream>>>(x, part, out, 64, 128, 0);
  nhead<<<(512 * 601 + 255) / 256, 256, 0, stream>>>(x, timet, out + 32768, NUM_TIMES, 256, 128);
  nhead<<<(512 * 360 + 255) / 256, 256, 0, stream>>>(x, f0t, out + 32768 + 307712, NUM_F0, 384, 384);
}

// Round 16
// 4622.212 us; speedup vs baseline: 242.7100x; 1.4284x over previous
//
#include <hip/hip_runtime.h>
#include <hip/hip_bf16.h>
#include <math.h>

#define D_P 128
#define D_T 256
#define D_F 384
#define DIM 768
#define NUM_TIMES 601
#define NUM_F0 360
#define NHEAD 12
#define HD 64
#define NLAYERS 6
#define DFF 2048
#define CTX 1024
#define SEQ 1088
#define BATCH 8
#define ROWS (BATCH*SEQ)
#define TDIM3 (3*DIM)

// Required template symbol; also the guard-path fill kernel.
__global__ void SequenceModel_30425548325019_kernel(unsigned short* out, int n, unsigned short v) {
  int i = blockIdx.x * 256 + threadIdx.x;
  if (i < n) out[i] = v;
}

typedef __attribute__((ext_vector_type(8))) short bfrag;   // 8 bf16 = 4 VGPR
typedef __attribute__((ext_vector_type(4))) float f32x4;   // acc

__device__ inline short f2bf(float f) {
  unsigned u = __float_as_uint(f);
  unsigned r = (u + 0x7FFFu + ((u >> 16) & 1u)) >> 16;  // RNE
  return (short)r;
}

// ---------------- embedding ----------------
__global__ __launch_bounds__(256) void embed_kernel(
    const int* __restrict__ cp, const float* __restrict__ ct,
    const int* __restrict__ cf, const float* __restrict__ part,
    const float* __restrict__ f0t, const float* __restrict__ pad,
    float* __restrict__ x) {
  int idx = blockIdx.x * 256 + threadIdx.x;
  if (idx >= ROWS * DIM) return;
  int d = idx % DIM;
  int row = idx / DIM;
  int b = row / SEQ, s = row - b * SEQ;
  float v;
  if (s >= CTX) {
    v = pad[d];
  } else if (d < D_P) {
    v = part[cp[b * CTX + s] * D_P + d];
  } else if (d < D_P + D_T) {
    int j = d - D_P;
    int i2 = j >> 1;
    float wk = powf(10000.f, -(float)i2 / (float)D_T) * ((float)D_T / (float)NUM_TIMES);
    float ang = ct[b * CTX + s] * wk;
    v = (j & 1) ? cosf(ang) : sinf(ang);
  } else {
    v = f0t[cf[b * CTX + s] * D_F + (d - D_P - D_T)];
  }
  x[idx] = v;
}

// ---------------- bf16 MFMA NT GEMM (unchanged from R15) ----------------
#define BM 128
#define BN 128
#define BK 32

__global__ __launch_bounds__(256) void gemm_mfma(
    const float* __restrict__ A, const float* __restrict__ B,
    const float* __restrict__ bias, const float* __restrict__ resid,
    float* __restrict__ C, int M, int N, int K, int relu) {
  __shared__ short As[4 * BM * 8];
  __shared__ short Bs[4 * BN * 8];
  const int tid = threadIdx.x;
  const int wave = tid >> 6, lane = tid & 63;
  const int wr = wave >> 1, wc = wave & 1;
  const int l15 = lane & 15, l4 = lane >> 4;
  const int m0 = blockIdx.y * BM, n0 = blockIdx.x * BN;
  f32x4 acc[4][4] = {};

  for (int k0 = 0; k0 < K; k0 += BK) {
    __syncthreads();
    #pragma unroll
    for (int i = 0; i < 2; ++i) {
      int s = tid + 256 * i;
      int row = s & 127, kg = s >> 7;
      const float* ap = A + (size_t)(m0 + row) * K + k0 + kg * 8;
      const float* bp = B + (size_t)(n0 + row) * K + k0 + kg * 8;
      float4 a0 = *(const float4*)ap;
      float4 a1 = *(const float4*)(ap + 4);
      float4 b0 = *(const float4*)bp;
      float4 b1 = *(const float4*)(bp + 4);
      short* da = &As[(kg * BM + row) * 8];
      short* db = &Bs[(kg * BN + row) * 8];
      da[0] = f2bf(a0.x); da[1] = f2bf(a0.y); da[2] = f2bf(a0.z); da[3] = f2bf(a0.w);
      da[4] = f2bf(a1.x); da[5] = f2bf(a1.y); da[6] = f2bf(a1.z); da[7] = f2bf(a1.w);
      db[0] = f2bf(b0.x); db[1] = f2bf(b0.y); db[2] = f2bf(b0.z); db[3] = f2bf(b0.w);
      db[4] = f2bf(b1.x); db[5] = f2bf(b1.y); db[6] = f2bf(b1.z); db[7] = f2bf(b1.w);
    }
    __syncthreads();
    bfrag a[4], b[4];
    #pragma unroll
    for (int f = 0; f < 4; ++f) {
      a[f] = *(const bfrag*)&As[(l4 * BM + wr * 64 + f * 16 + l15) * 8];
      b[f] = *(const bfrag*)&Bs[(l4 * BN + wc * 64 + f * 16 + l15) * 8];
    }
    #pragma unroll
    for (int i = 0; i < 4; ++i)
      #pragma unroll
      for (int j = 0; j < 4; ++j)
        acc[i][j] = __builtin_amdgcn_mfma_f32_16x16x32_bf16(a[i], b[j], acc[i][j], 0, 0, 0);
  }
  #pragma unroll
  for (int i = 0; i < 4; ++i) {
    int mbase = m0 + wr * 64 + i * 16 + l4 * 4;
    #pragma unroll
    for (int j = 0; j < 4; ++j) {
      int n = n0 + wc * 64 + j * 16 + l15;
      float bv = bias[n];
      #pragma unroll
      for (int r = 0; r < 4; ++r) {
        int m = mbase + r;
        float v = acc[i][j][r] + bv;
        if (resid) v += resid[(size_t)m * N + n];
        if (relu) v = fmaxf(v, 0.f);
        C[(size_t)m * N + n] = v;
      }
    }
  }
}

// ---------------- MFMA flash attention ----------------
// Block = 256 thr (4 waves) per (b, h, 32-q-tile). K-tiles of 32.
// QK^T + PV on mfma_f32_16x16x32_bf16; online softmax fp32 in between.
__global__ __launch_bounds__(256) void attn_mfma(const float* __restrict__ qkv,
                                                 float* __restrict__ out) {
  const int qt = blockIdx.x, h = blockIdx.y, b = blockIdx.z;
  const int q0 = qt * 32;
  __shared__ short Qs[8 * 32 * 8];   // [kg(8)][row(32)][8]
  __shared__ short Ks[8 * 32 * 8];
  __shared__ short Vt[4 * 64 * 8];   // [kg(4)][d(64)][8]  (k-transposed V)
  __shared__ short Ps[4 * 32 * 8];   // [kg(4)][q(32)][8]
  __shared__ float Ss[32][33];
  __shared__ float alphaS[32], linvS[32];
  __shared__ float Os[32][68];
  const int tid = threadIdx.x;
  const int wave = tid >> 6, lane = tid & 63;
  const int l15 = lane & 15, l4 = lane >> 4;
  const int srow = tid >> 3;   // staging: row 0..31
  const int skg = tid & 7;     // staging: 8-elem group 0..7
  const int qr = tid >> 3, c = tid & 7;   // softmax role
  const int qg = wave >> 1;               // PV role: q-half
  const int dgb = (wave & 1) * 2;         // PV role: d-group base
  const int wq = wave >> 1, wk = wave & 1;  // QK role

  // stage Q (scaled)
  {
    const float* qp = qkv + (size_t)(b * SEQ + q0 + srow) * TDIM3 + h * HD + skg * 8;
    float4 a = *(const float4*)qp;
    float4 bb = *(const float4*)(qp + 4);
    short* d = &Qs[(skg * 32 + srow) * 8];
    d[0] = f2bf(a.x * 0.125f); d[1] = f2bf(a.y * 0.125f); d[2] = f2bf(a.z * 0.125f); d[3] = f2bf(a.w * 0.125f);
    d[4] = f2bf(bb.x * 0.125f); d[5] = f2bf(bb.y * 0.125f); d[6] = f2bf(bb.z * 0.125f); d[7] = f2bf(bb.w * 0.125f);
  }
  float mrun = -1e30f, lrun = 0.f;
  f32x4 o0 = {}, o1 = {};
  const int qglob = q0 + qr;
  const int nkt = (q0 < CTX) ? (qt + 1) : (CTX / 32);

  for (int kt = 0; kt < nkt; ++kt) {
    const int k0 = kt * 32;
    __syncthreads();   // Ks/Vt safe to overwrite (prev PV done)
    // stage K and V(transposed)
    {
      const float* kp = qkv + (size_t)(b * SEQ + k0 + srow) * TDIM3 + DIM + h * HD + skg * 8;
      float4 a = *(const float4*)kp;
      float4 bb = *(const float4*)(kp + 4);
      short* d = &Ks[(skg * 32 + srow) * 8];
      d[0] = f2bf(a.x); d[1] = f2bf(a.y); d[2] = f2bf(a.z); d[3] = f2bf(a.w);
      d[4] = f2bf(bb.x); d[5] = f2bf(bb.y); d[6] = f2bf(bb.z); d[7] = f2bf(bb.w);
      const float* vp = kp + DIM;
      float4 v0 = *(const float4*)vp;
      float4 v1 = *(const float4*)(vp + 4);
      int kg = srow >> 3, j = srow & 7, db = skg * 8;
      Vt[(kg * 64 + db + 0) * 8 + j] = f2bf(v0.x);
      Vt[(kg * 64 + db + 1) * 8 + j] = f2bf(v0.y);
      Vt[(kg * 64 + db + 2) * 8 + j] = f2bf(v0.z);
      Vt[(kg * 64 + db + 3) * 8 + j] = f2bf(v0.w);
      Vt[(kg * 64 + db + 4) * 8 + j] = f2bf(v1.x);
      Vt[(kg * 64 + db + 5) * 8 + j] = f2bf(v1.y);
      Vt[(kg * 64 + db + 6) * 8 + j] = f2bf(v1.z);
      Vt[(kg * 64 + db + 7) * 8 + j] = f2bf(v1.w);
    }
    __syncthreads();
    // QK^T: each wave one 16x16 S-frag over k-dim 64 (2 MFMAs)
    {
      f32x4 s = {};
      #pragma unroll
      for (int t = 0; t < 2; ++t) {
        bfrag a = *(const bfrag*)&Qs[((t * 4 + l4) * 32 + wq * 16 + l15) * 8];
        bfrag bb = *(const bfrag*)&Ks[((t * 4 + l4) * 32 + wk * 16 + l15) * 8];
        s = __builtin_amdgcn_mfma_f32_16x16x32_bf16(a, bb, s, 0, 0, 0);
      }
      #pragma unroll
      for (int r = 0; r < 4; ++r)
        Ss[wq * 16 + l4 * 4 + r][wk * 16 + l15] = s[r];
    }
    __syncthreads();
    // online softmax (8 lanes per q-row, 4 k each)
    {
      float sv[4];
      #pragma unroll
      for (int i = 0; i < 4; ++i) {
        int kg = k0 + c * 4 + i;
        float s = Ss[qr][c * 4 + i];
        bool allowed = (qglob < CTX) ? (kg <= qglob) : true;
        sv[i] = allowed ? s : -1e30f;
      }
      float tm = fmaxf(fmaxf(sv[0], sv[1]), fmaxf(sv[2], sv[3]));
      tm = fmaxf(tm, __shfl_xor(tm, 1));
      tm = fmaxf(tm, __shfl_xor(tm, 2));
      tm = fmaxf(tm, __shfl_xor(tm, 4));
      float mn = fmaxf(mrun, tm);
      float alpha = __expf(mrun - mn);
      float p0 = __expf(sv[0] - mn), p1 = __expf(sv[1] - mn);
      float p2 = __expf(sv[2] - mn), p3 = __expf(sv[3] - mn);
      float ls = p0 + p1 + p2 + p3;
      ls += __shfl_xor(ls, 1); ls += __shfl_xor(ls, 2); ls += __shfl_xor(ls, 4);
      lrun = lrun * alpha + ls;
      mrun = mn;
      if (c == 0) alphaS[qr] = alpha;
      short* pd = &Ps[((c >> 1) * 32 + qr) * 8 + (c & 1) * 4];
      pd[0] = f2bf(p0); pd[1] = f2bf(p1); pd[2] = f2bf(p2); pd[3] = f2bf(p3);
    }
    __syncthreads();
    // PV: rescale O frags then accumulate
    {
      #pragma unroll
      for (int r = 0; r < 4; ++r) {
        float ar = alphaS[qg * 16 + l4 * 4 + r];
        o0[r] *= ar;
        o1[r] *= ar;
      }
      bfrag pa = *(const bfrag*)&Ps[(l4 * 32 + qg * 16 + l15) * 8];
      bfrag v0 = *(const bfrag*)&Vt[(l4 * 64 + (dgb + 0) * 16 + l15) * 8];
      bfrag v1 = *(const bfrag*)&Vt[(l4 * 64 + (dgb + 1) * 16 + l15) * 8];
      o0 = __builtin_amdgcn_mfma_f32_16x16x32_bf16(pa, v0, o0, 0, 0, 0);
      o1 = __builtin_amdgcn_mfma_f32_16x16x32_bf16(pa, v1, o1, 0, 0, 0);
    }
  }
  if (c == 0) linvS[qr] = 1.f / lrun;
  __syncthreads();
  #pragma unroll
  for (int r = 0; r < 4; ++r) {
    float li = linvS[qg * 16 + l4 * 4 + r];
    Os[qg * 16 + l4 * 4 + r][(dgb + 0) * 16 + l15] = o0[r] * li;
    Os[qg * 16 + l4 * 4 + r][(dgb + 1) * 16 + l15] = o1[r] * li;
  }
  __syncthreads();
  {
    float* dst = out + (size_t)(b * SEQ + q0 + srow) * DIM + h * HD + skg * 8;
    const float* s = &Os[srow][skg * 8];
    float4 t0 = {s[0], s[1], s[2], s[3]};
    float4 t1 = {s[4], s[5], s[6], s[7]};
    *(float4*)dst = t0;
    *(float4*)(dst + 4) = t1;
  }
}

// ---------------- layernorm ----------------
__global__ __launch_bounds__(256) void ln_kernel(const float* __restrict__ in,
                                                 const float* __restrict__ g,
                                                 const float* __restrict__ bb,
                                                 float* __restrict__ out) {
  const int row = blockIdx.x;
  const float* p = in + (size_t)row * DIM;
  const int tid = threadIdx.x;
  float v0 = p[tid], v1 = p[tid + 256], v2 = p[tid + 512];
  float s1 = v0 + v1 + v2;
  float s2 = v0 * v0 + v1 * v1 + v2 * v2;
  #pragma unroll
  for (int off = 32; off >= 1; off >>= 1) {
    s1 += __shfl_down(s1, off);
    s2 += __shfl_down(s2, off);
  }
  __shared__ float r1[4], r2[4];
  int wid = tid >> 6;
  if ((tid & 63) == 0) { r1[wid] = s1; r2[wid] = s2; }
  __syncthreads();
  s1 = r1[0] + r1[1] + r1[2] + r1[3];
  s2 = r2[0] + r2[1] + r2[2] + r2[3];
  const float mu = s1 * (1.f / DIM);
  const float var = s2 * (1.f / DIM) - mu * mu;
  const float rs = rsqrtf(var + 1e-5f);
  float* q = out + (size_t)row * DIM;
  q[tid]       = (v0 - mu) * rs * g[tid]       + bb[tid];
  q[tid + 256] = (v1 - mu) * rs * g[tid + 256] + bb[tid + 256];
  q[tid + 512] = (v2 - mu) * rs * g[tid + 512] + bb[tid + 512];
}

// ---------------- output heads (fp32 out) ----------------
__global__ __launch_bounds__(256) void nhead(const float* __restrict__ x,
                                             const float* __restrict__ T,
                                             float* __restrict__ out,
                                             int N, int K, int coloff) {
  int idx = blockIdx.x * 256 + threadIdx.x;
  if (idx >= 512 * N) return;
  int mm = idx / N, n = idx - mm * N;
  int b = mm >> 6, rr = mm & 63;
  const float* xp = x + (size_t)(b * SEQ + CTX + rr) * DIM + coloff;
  const float* tp = T + (size_t)n * K;
  float acc = 0.f;
  for (int k = 0; k < K; ++k) acc = fmaf(xp[k], tp[k], acc);
  out[idx] = acc;
}

extern "C" void kernel_launch(void* const* d_in, const int* in_sizes, int n_in,
                              void* d_out, int out_size, void* d_ws, size_t ws_size,
                              hipStream_t stream) {
  size_t need = ((size_t)ROWS * DIM * 6) * sizeof(float);
  if (ws_size < need) {
    SequenceModel_30425548325019_kernel<<<(out_size + 255) / 256, 256, 0, stream>>>(
        (unsigned short*)d_out, out_size, (unsigned short)0x4280);
    return;
  }

  const int*   cp    = (const int*)d_in[0];
  const float* ct    = (const float*)d_in[1];
  const int*   cf    = (const int*)d_in[2];
  const float* part  = (const float*)d_in[3];
  const float* timet = (const float*)d_in[4];
  const float* f0t   = (const float*)d_in[5];
  const float* pad   = (const float*)d_in[6];
  const float* Wqkv  = (const float*)d_in[7];
  const float* bqkv  = (const float*)d_in[8];
  const float* Wo    = (const float*)d_in[9];
  const float* bo    = (const float*)d_in[10];
  const float* ln1g  = (const float*)d_in[11];
  const float* ln1b  = (const float*)d_in[12];
  const float* W1    = (const float*)d_in[13];
  const float* b1    = (const float*)d_in[14];
  const float* W2    = (const float*)d_in[15];
  const float* b2    = (const float*)d_in[16];
  const float* ln2g  = (const float*)d_in[17];
  const float* ln2b  = (const float*)d_in[18];

  float* x    = (float*)d_ws;
  float* buf  = x + (size_t)ROWS * DIM;
  float* ctxb = buf + (size_t)ROWS * TDIM3;
  float* tmp  = ctxb + (size_t)ROWS * DIM;

  embed_kernel<<<(ROWS * DIM + 255) / 256, 256, 0, stream>>>(cp, ct, cf, part, f0t, pad, x);

  for (int l = 0; l < NLAYERS; ++l) {
    gemm_mfma<<<dim3(TDIM3 / BN, ROWS / BM), 256, 0, stream>>>(
        x, Wqkv + (size_t)l * TDIM3 * DIM, bqkv + l * TDIM3, nullptr, buf,
        ROWS, TDIM3, DIM, 0);
    attn_mfma<<<dim3(SEQ / 32, NHEAD, BATCH), 256, 0, stream>>>(buf, ctxb);
    gemm_mfma<<<dim3(DIM / BN, ROWS / BM), 256, 0, stream>>>(
        ctxb, Wo + (size_t)l * DIM * DIM, bo + l * DIM, x, tmp,
        ROWS, DIM, DIM, 0);
    ln_kernel<<<ROWS, 256, 0, stream>>>(tmp, ln1g + l * DIM, ln1b + l * DIM, x);
    gemm_mfma<<<dim3(DFF / BN, ROWS / BM), 256, 0, stream>>>(
        x, W1 + (size_t)l * DFF * DIM, b1 + l * DFF, nullptr, buf,
        ROWS, DFF, DIM, 1);
    gemm_mfma<<<dim3(DIM / BN, ROWS / BM), 256, 0, stream>>>(
        buf, W2 + (size_t)l * DIM * DFF, b2 + l * DIM, x, tmp,
        ROWS, DIM, DFF, 0);
    ln_kernel<<<ROWS, 256, 0, stream>>>(tmp, ln2g + l * DIM, ln2b + l * DIM, x);
  }

  float* out = (float*)d_out;
  nhead<<<(512 * 64 + 255) / 256, 256, 0, stream>>>(x, part, out, 64, 128, 0);
  nhead<<<(512 * 601 + 255) / 256, 256, 0, stream>>>(x, timet, out + 32768, NUM_TIMES, 256, 128);
  nhead<<<(512 * 360 + 255) / 256, 256, 0, stream>>>(x, f0t, out + 32768 + 307712, NUM_F0, 384, 384);
}

// Round 17
// 4292.599 us; speedup vs baseline: 261.3467x; 1.0768x over previous
//
#include <hip/hip_runtime.h>
#include <hip/hip_bf16.h>
#include <math.h>

#define D_P 128
#define D_T 256
#define D_F 384
#define DIM 768
#define NUM_TIMES 601
#define NUM_F0 360
#define NHEAD 12
#define HD 64
#define NLAYERS 6
#define DFF 2048
#define CTX 1024
#define SEQ 1088
#define BATCH 8
#define ROWS (BATCH*SEQ)
#define TDIM3 (3*DIM)
#define PREDROWS 512

// Required template symbol; also the guard-path fill kernel.
__global__ void SequenceModel_30425548325019_kernel(unsigned short* out, int n, unsigned short v) {
  int i = blockIdx.x * 256 + threadIdx.x;
  if (i < n) out[i] = v;
}

typedef __attribute__((ext_vector_type(8))) short bfrag;
typedef __attribute__((ext_vector_type(4))) float f32x4;

__device__ inline short f2bf(float f) {
  unsigned u = __float_as_uint(f);
  unsigned r = (u + 0x7FFFu + ((u >> 16) & 1u)) >> 16;  // RNE
  return (short)r;
}

// ---------------- embedding ----------------
__global__ __launch_bounds__(256) void embed_kernel(
    const int* __restrict__ cp, const float* __restrict__ ct,
    const int* __restrict__ cf, const float* __restrict__ part,
    const float* __restrict__ f0t, const float* __restrict__ pad,
    float* __restrict__ x) {
  int idx = blockIdx.x * 256 + threadIdx.x;
  if (idx >= ROWS * DIM) return;
  int d = idx % DIM;
  int row = idx / DIM;
  int b = row / SEQ, s = row - b * SEQ;
  float v;
  if (s >= CTX) {
    v = pad[d];
  } else if (d < D_P) {
    v = part[cp[b * CTX + s] * D_P + d];
  } else if (d < D_P + D_T) {
    int j = d - D_P;
    int i2 = j >> 1;
    float wk = powf(10000.f, -(float)i2 / (float)D_T) * ((float)D_T / (float)NUM_TIMES);
    float ang = ct[b * CTX + s] * wk;
    v = (j & 1) ? cosf(ang) : sinf(ang);
  } else {
    v = f0t[cf[b * CTX + s] * D_F + (d - D_P - D_T)];
  }
  x[idx] = v;
}

// ---------------- bf16 MFMA NT GEMM (verified R15 structure) ----------------
#define BM 128
#define BN 128
#define BK 32

__global__ __launch_bounds__(256) void gemm_mfma(
    const float* __restrict__ A, const float* __restrict__ B,
    const float* __restrict__ bias, const float* __restrict__ resid,
    float* __restrict__ C, int M, int N, int K, int relu) {
  __shared__ short As[4 * BM * 8];
  __shared__ short Bs[4 * BN * 8];
  const int tid = threadIdx.x;
  const int wave = tid >> 6, lane = tid & 63;
  const int wr = wave >> 1, wc = wave & 1;
  const int l15 = lane & 15, l4 = lane >> 4;
  const int m0 = blockIdx.y * BM, n0 = blockIdx.x * BN;
  f32x4 acc[4][4] = {};

  for (int k0 = 0; k0 < K; k0 += BK) {
    __syncthreads();
    #pragma unroll
    for (int i = 0; i < 2; ++i) {
      int s = tid + 256 * i;
      int row = s & 127, kg = s >> 7;
      const float* ap = A + (size_t)(m0 + row) * K + k0 + kg * 8;
      const float* bp = B + (size_t)(n0 + row) * K + k0 + kg * 8;
      float4 a0 = *(const float4*)ap;
      float4 a1 = *(const float4*)(ap + 4);
      float4 b0 = *(const float4*)bp;
      float4 b1 = *(const float4*)(bp + 4);
      short* da = &As[(kg * BM + row) * 8];
      short* db = &Bs[(kg * BN + row) * 8];
      da[0] = f2bf(a0.x); da[1] = f2bf(a0.y); da[2] = f2bf(a0.z); da[3] = f2bf(a0.w);
      da[4] = f2bf(a1.x); da[5] = f2bf(a1.y); da[6] = f2bf(a1.z); da[7] = f2bf(a1.w);
      db[0] = f2bf(b0.x); db[1] = f2bf(b0.y); db[2] = f2bf(b0.z); db[3] = f2bf(b0.w);
      db[4] = f2bf(b1.x); db[5] = f2bf(b1.y); db[6] = f2bf(b1.z); db[7] = f2bf(b1.w);
    }
    __syncthreads();
    bfrag a[4], b[4];
    #pragma unroll
    for (int f = 0; f < 4; ++f) {
      a[f] = *(const bfrag*)&As[(l4 * BM + wr * 64 + f * 16 + l15) * 8];
      b[f] = *(const bfrag*)&Bs[(l4 * BN + wc * 64 + f * 16 + l15) * 8];
    }
    #pragma unroll
    for (int i = 0; i < 4; ++i)
      #pragma unroll
      for (int j = 0; j < 4; ++j)
        acc[i][j] = __builtin_amdgcn_mfma_f32_16x16x32_bf16(a[i], b[j], acc[i][j], 0, 0, 0);
  }
  #pragma unroll
  for (int i = 0; i < 4; ++i) {
    int mbase = m0 + wr * 64 + i * 16 + l4 * 4;
    #pragma unroll
    for (int j = 0; j < 4; ++j) {
      int n = n0 + wc * 64 + j * 16 + l15;
      float bv = bias[n];
      #pragma unroll
      for (int r = 0; r < 4; ++r) {
        int m = mbase + r;
        float v = acc[i][j][r] + bv;
        if (resid) v += resid[(size_t)m * N + n];
        if (relu) v = fmaxf(v, 0.f);
        C[(size_t)m * N + n] = v;
      }
    }
  }
}

// ---------------- gather pred rows into contiguous buffer ----------------
__global__ __launch_bounds__(256) void gather_pred(const float* __restrict__ x,
                                                   float* __restrict__ xp) {
  int idx = blockIdx.x * 256 + threadIdx.x;
  if (idx >= PREDROWS * DIM) return;
  int r = idx / DIM, d = idx - r * DIM;
  int b = r >> 6, rr = r & 63;
  xp[idx] = x[(size_t)(b * SEQ + CTX + rr) * DIM + d];
}

// ---------------- head GEMM (MFMA, N-guarded): C[512,N] = xp[:,coloff:+K] * T[N,K]^T
__global__ __launch_bounds__(256) void head_mfma(
    const float* __restrict__ A, const float* __restrict__ B,
    float* __restrict__ C, int N, int K, int lda, int coloff) {
  __shared__ short As[4 * BM * 8];
  __shared__ short Bs[4 * BN * 8];
  const int tid = threadIdx.x;
  const int wave = tid >> 6, lane = tid & 63;
  const int wr = wave >> 1, wc = wave & 1;
  const int l15 = lane & 15, l4 = lane >> 4;
  const int m0 = blockIdx.y * BM, n0 = blockIdx.x * BN;
  f32x4 acc[4][4] = {};

  for (int k0 = 0; k0 < K; k0 += BK) {
    __syncthreads();
    #pragma unroll
    for (int i = 0; i < 2; ++i) {
      int s = tid + 256 * i;
      int row = s & 127, kg = s >> 7;
      const float* ap = A + (size_t)(m0 + row) * lda + coloff + k0 + kg * 8;
      float4 a0 = *(const float4*)ap;
      float4 a1 = *(const float4*)(ap + 4);
      short* da = &As[(kg * BM + row) * 8];
      da[0] = f2bf(a0.x); da[1] = f2bf(a0.y); da[2] = f2bf(a0.z); da[3] = f2bf(a0.w);
      da[4] = f2bf(a1.x); da[5] = f2bf(a1.y); da[6] = f2bf(a1.z); da[7] = f2bf(a1.w);
      short* db = &Bs[(kg * BN + row) * 8];
      if (n0 + row < N) {
        const float* bp = B + (size_t)(n0 + row) * K + k0 + kg * 8;
        float4 b0 = *(const float4*)bp;
        float4 b1 = *(const float4*)(bp + 4);
        db[0] = f2bf(b0.x); db[1] = f2bf(b0.y); db[2] = f2bf(b0.z); db[3] = f2bf(b0.w);
        db[4] = f2bf(b1.x); db[5] = f2bf(b1.y); db[6] = f2bf(b1.z); db[7] = f2bf(b1.w);
      } else {
        db[0] = 0; db[1] = 0; db[2] = 0; db[3] = 0;
        db[4] = 0; db[5] = 0; db[6] = 0; db[7] = 0;
      }
    }
    __syncthreads();
    bfrag a[4], b[4];
    #pragma unroll
    for (int f = 0; f < 4; ++f) {
      a[f] = *(const bfrag*)&As[(l4 * BM + wr * 64 + f * 16 + l15) * 8];
      b[f] = *(const bfrag*)&Bs[(l4 * BN + wc * 64 + f * 16 + l15) * 8];
    }
    #pragma unroll
    for (int i = 0; i < 4; ++i)
      #pragma unroll
      for (int j = 0; j < 4; ++j)
        acc[i][j] = __builtin_amdgcn_mfma_f32_16x16x32_bf16(a[i], b[j], acc[i][j], 0, 0, 0);
  }
  #pragma unroll
  for (int i = 0; i < 4; ++i) {
    int mbase = m0 + wr * 64 + i * 16 + l4 * 4;
    #pragma unroll
    for (int j = 0; j < 4; ++j) {
      int n = n0 + wc * 64 + j * 16 + l15;
      if (n >= N) continue;
      #pragma unroll
      for (int r = 0; r < 4; ++r)
        C[(size_t)(mbase + r) * N + n] = acc[i][j][r];
    }
  }
}

// ---------------- MFMA flash attention, QBLK=64 ----------------
// Block = 256 thr (4 waves) per (b, h, 64-q-tile). K-tiles of 32.
#define QBLK 64
__global__ __launch_bounds__(256) void attn_mfma(const float* __restrict__ qkv,
                                                 float* __restrict__ out) {
  const int qt = blockIdx.x, h = blockIdx.y, b = blockIdx.z;
  const int q0 = qt * QBLK;
  // Qs/Ks: diagonal-skewed [kg][row] 16B units. Vt/Ps: stride-9 shorts.
  __shared__ short Qs[8 * 64 * 8];
  __shared__ short Ks[8 * 32 * 8];
  __shared__ short Vt[4 * 64 * 9];   // (kg*64+d)*9 + j ; V[k=kg*8+j][d]
  __shared__ short Ps[4 * 64 * 9];   // (kg*64+q)*9 + j ; P[q][k=kg*8+j]
  __shared__ float SO[64 * 68];      // Ss: row*33+col ; Os: row*68+d
  __shared__ float alphaS[64], linvS[64];
  const int tid = threadIdx.x;
  const int wave = tid >> 6, lane = tid & 63;
  const int l15 = lane & 15, l4 = lane >> 4;
  const int srow = tid >> 3, skg = tid & 7;     // staging roles
  const int smrow = tid >> 2, smc = tid & 3;    // softmax roles
  const int qf = wave;                          // q-fragment owner

  // stage Q (scaled), rows q0..q0+63
  #pragma unroll
  for (int i = 0; i < 2; ++i) {
    int s = tid + 256 * i;
    int r = s >> 3, kg = s & 7;
    const float* qp = qkv + (size_t)(b * SEQ + q0 + r) * TDIM3 + h * HD + kg * 8;
    float4 a = *(const float4*)qp;
    float4 bb = *(const float4*)(qp + 4);
    short* d = &Qs[(kg * 64 + ((r + kg) & 63)) * 8];
    d[0] = f2bf(a.x * 0.125f); d[1] = f2bf(a.y * 0.125f); d[2] = f2bf(a.z * 0.125f); d[3] = f2bf(a.w * 0.125f);
    d[4] = f2bf(bb.x * 0.125f); d[5] = f2bf(bb.y * 0.125f); d[6] = f2bf(bb.z * 0.125f); d[7] = f2bf(bb.w * 0.125f);
  }
  float mrun = -1e30f, lrun = 0.f;
  f32x4 o[4] = {};
  const int nkt = (q0 < CTX) ? (q0 + QBLK) / 32 : (CTX / 32);

  for (int kt = 0; kt < nkt; ++kt) {
    const int k0 = kt * 32;
    __syncthreads();
    // stage K (skewed) and V (transposed, stride-9)
    {
      const float* kp = qkv + (size_t)(b * SEQ + k0 + srow) * TDIM3 + DIM + h * HD + skg * 8;
      float4 a = *(const float4*)kp;
      float4 bb = *(const float4*)(kp + 4);
      short* d = &Ks[(skg * 32 + ((srow + skg) & 31)) * 8];
      d[0] = f2bf(a.x); d[1] = f2bf(a.y); d[2] = f2bf(a.z); d[3] = f2bf(a.w);
      d[4] = f2bf(bb.x); d[5] = f2bf(bb.y); d[6] = f2bf(bb.z); d[7] = f2bf(bb.w);
      const float* vp = kp + DIM;
      float4 v0 = *(const float4*)vp;
      float4 v1 = *(const float4*)(vp + 4);
      int kg = srow >> 3, j = srow & 7, db = skg * 8;
      float vv[8] = {v0.x, v0.y, v0.z, v0.w, v1.x, v1.y, v1.z, v1.w};
      #pragma unroll
      for (int e = 0; e < 8; ++e)
        Vt[(kg * 64 + db + e) * 9 + j] = f2bf(vv[e]);
    }
    __syncthreads();
    // QK^T: wave qf computes S rows qf*16..+15, both k-halves
    #pragma unroll
    for (int jk = 0; jk < 2; ++jk) {
      f32x4 s = {};
      #pragma unroll
      for (int t = 0; t < 2; ++t) {
        int kg = t * 4 + l4;
        int ar = qf * 16 + l15;
        bfrag a = *(const bfrag*)&Qs[(kg * 64 + ((ar + kg) & 63)) * 8];
        int br = jk * 16 + l15;
        bfrag bb = *(const bfrag*)&Ks[(kg * 32 + ((br + kg) & 31)) * 8];
        s = __builtin_amdgcn_mfma_f32_16x16x32_bf16(a, bb, s, 0, 0, 0);
      }
      #pragma unroll
      for (int r = 0; r < 4; ++r)
        SO[(qf * 16 + l4 * 4 + r) * 33 + jk * 16 + l15] = s[r];
    }
    __syncthreads();
    // online softmax: 4 lanes per row, 8 k each (lane smc covers k-group smc)
    {
      const int qglob = q0 + smrow;
      float p[8];
      float tm = -1e30f;
      #pragma unroll
      for (int i = 0; i < 8; ++i) {
        int kg = k0 + smc * 8 + i;
        float s = SO[smrow * 33 + smc * 8 + i];
        bool allowed = (qglob < CTX) ? (kg <= qglob) : true;
        p[i] = allowed ? s : -1e30f;
        tm = fmaxf(tm, p[i]);
      }
      tm = fmaxf(tm, __shfl_xor(tm, 1));
      tm = fmaxf(tm, __shfl_xor(tm, 2));
      float mn = fmaxf(mrun, tm);
      float alpha = __expf(mrun - mn);
      float ls = 0.f;
      #pragma unroll
      for (int i = 0; i < 8; ++i) { p[i] = __expf(p[i] - mn); ls += p[i]; }
      ls += __shfl_xor(ls, 1);
      ls += __shfl_xor(ls, 2);
      lrun = lrun * alpha + ls;
      mrun = mn;
      if (smc == 0) alphaS[smrow] = alpha;
      short* pd = &Ps[(smc * 64 + smrow) * 9];
      #pragma unroll
      for (int i = 0; i < 8; ++i) pd[i] = f2bf(p[i]);
    }
    __syncthreads();
    // PV: wave qf owns O rows qf*16..+15, all 4 d-frags
    {
      #pragma unroll
      for (int r = 0; r < 4; ++r) {
        float ar = alphaS[qf * 16 + l4 * 4 + r];
        #pragma unroll
        for (int df = 0; df < 4; ++df) o[df][r] *= ar;
      }
      bfrag pa = *(const bfrag*)&Ps[(l4 * 64 + qf * 16 + l15) * 9];
      #pragma unroll
      for (int df = 0; df < 4; ++df) {
        bfrag v = *(const bfrag*)&Vt[(l4 * 64 + df * 16 + l15) * 9];
        o[df] = __builtin_amdgcn_mfma_f32_16x16x32_bf16(pa, v, o[df], 0, 0, 0);
      }
    }
  }
  if (smc == 0) linvS[smrow] = 1.f / lrun;
  __syncthreads();
  #pragma unroll
  for (int r = 0; r < 4; ++r) {
    float li = linvS[qf * 16 + l4 * 4 + r];
    #pragma unroll
    for (int df = 0; df < 4; ++df)
      SO[(qf * 16 + l4 * 4 + r) * 68 + df * 16 + l15] = o[df][r] * li;
  }
  __syncthreads();
  #pragma unroll
  for (int i = 0; i < 2; ++i) {
    int s = tid + 256 * i;
    int r = s >> 3, kg = s & 7;
    float* dst = out + (size_t)(b * SEQ + q0 + r) * DIM + h * HD + kg * 8;
    const float* sp = &SO[r * 68 + kg * 8];
    float4 t0 = {sp[0], sp[1], sp[2], sp[3]};
    float4 t1 = {sp[4], sp[5], sp[6], sp[7]};
    *(float4*)dst = t0;
    *(float4*)(dst + 4) = t1;
  }
}

// ---------------- layernorm ----------------
__global__ __launch_bounds__(256) void ln_kernel(const float* __restrict__ in,
                                                 const float* __restrict__ g,
                                                 const float* __restrict__ bb,
                                                 float* __restrict__ out) {
  const int row = blockIdx.x;
  const float* p = in + (size_t)row * DIM;
  const int tid = threadIdx.x;
  float v0 = p[tid], v1 = p[tid + 256], v2 = p[tid + 512];
  float s1 = v0 + v1 + v2;
  float s2 = v0 * v0 + v1 * v1 + v2 * v2;
  #pragma unroll
  for (int off = 32; off >= 1; off >>= 1) {
    s1 += __shfl_down(s1, off);
    s2 += __shfl_down(s2, off);
  }
  __shared__ float r1[4], r2[4];
  int wid = tid >> 6;
  if ((tid & 63) == 0) { r1[wid] = s1; r2[wid] = s2; }
  __syncthreads();
  s1 = r1[0] + r1[1] + r1[2] + r1[3];
  s2 = r2[0] + r2[1] + r2[2] + r2[3];
  const float mu = s1 * (1.f / DIM);
  const float var = s2 * (1.f / DIM) - mu * mu;
  const float rs = rsqrtf(var + 1e-5f);
  float* q = out + (size_t)row * DIM;
  q[tid]       = (v0 - mu) * rs * g[tid]       + bb[tid];
  q[tid + 256] = (v1 - mu) * rs * g[tid + 256] + bb[tid + 256];
  q[tid + 512] = (v2 - mu) * rs * g[tid + 512] + bb[tid + 512];
}

extern "C" void kernel_launch(void* const* d_in, const int* in_sizes, int n_in,
                              void* d_out, int out_size, void* d_ws, size_t ws_size,
                              hipStream_t stream) {
  size_t need = ((size_t)ROWS * DIM * 6 + (size_t)PREDROWS * DIM) * sizeof(float);
  if (ws_size < need) {
    SequenceModel_30425548325019_kernel<<<(out_size + 255) / 256, 256, 0, stream>>>(
        (unsigned short*)d_out, out_size, (unsigned short)0x4280);
    return;
  }

  const int*   cp    = (const int*)d_in[0];
  const float* ct    = (const float*)d_in[1];
  const int*   cf    = (const int*)d_in[2];
  const float* part  = (const float*)d_in[3];
  const float* timet = (const float*)d_in[4];
  const float* f0t   = (const float*)d_in[5];
  const float* pad   = (const float*)d_in[6];
  const float* Wqkv  = (const float*)d_in[7];
  const float* bqkv  = (const float*)d_in[8];
  const float* Wo    = (const float*)d_in[9];
  const float* bo    = (const float*)d_in[10];
  const float* ln1g  = (const float*)d_in[11];
  const float* ln1b  = (const float*)d_in[12];
  const float* W1    = (const float*)d_in[13];
  const float* b1    = (const float*)d_in[14];
  const float* W2    = (const float*)d_in[15];
  const float* b2    = (const float*)d_in[16];
  const float* ln2g  = (const float*)d_in[17];
  const float* ln2b  = (const float*)d_in[18];

  float* x    = (float*)d_ws;
  float* buf  = x + (size_t)ROWS * DIM;
  float* ctxb = buf + (size_t)ROWS * TDIM3;
  float* tmp  = ctxb + (size_t)ROWS * DIM;
  float* xp   = tmp + (size_t)ROWS * DIM;

  embed_kernel<<<(ROWS * DIM + 255) / 256, 256, 0, stream>>>(cp, ct, cf, part, f0t, pad, x);

  for (int l = 0; l < NLAYERS; ++l) {
    gemm_mfma<<<dim3(TDIM3 / BN, ROWS / BM), 256, 0, stream>>>(
        x, Wqkv + (size_t)l * TDIM3 * DIM, bqkv + l * TDIM3, nullptr, buf,
        ROWS, TDIM3, DIM, 0);
    attn_mfma<<<dim3(SEQ / QBLK, NHEAD, BATCH), 256, 0, stream>>>(buf, ctxb);
    gemm_mfma<<<dim3(DIM / BN, ROWS / BM), 256, 0, stream>>>(
        ctxb, Wo + (size_t)l * DIM * DIM, bo + l * DIM, x, tmp,
        ROWS, DIM, DIM, 0);
    ln_kernel<<<ROWS, 256, 0, stream>>>(tmp, ln1g + l * DIM, ln1b + l * DIM, x);
    gemm_mfma<<<dim3(DFF / BN, ROWS / BM), 256, 0, stream>>>(
        x, W1 + (size_t)l * DFF * DIM, b1 + l * DFF, nullptr, buf,
        ROWS, DFF, DIM, 1);
    gemm_mfma<<<dim3(DIM / BN, ROWS / BM), 256, 0, stream>>>(
        buf, W2 + (size_t)l * DIM * DFF, b2 + l * DIM, x, tmp,
        ROWS, DIM, DFF, 0);
    ln_kernel<<<ROWS, 256, 0, stream>>>(tmp, ln2g + l * DIM, ln2b + l * DIM, x);
  }

  float* out = (float*)d_out;
  gather_pred<<<(PREDROWS * DIM + 255) / 256, 256, 0, stream>>>(x, xp);
  head_mfma<<<dim3(1, PREDROWS / BM), 256, 0, stream>>>(xp, part, out, 64, 128, DIM, 0);
  head_mfma<<<dim3(5, PREDROWS / BM), 256, 0, stream>>>(xp, timet, out + 32768, NUM_TIMES, 256, DIM, 128);
  head_mfma<<<dim3(3, PREDROWS / BM), 256, 0, stream>>>(xp, f0t, out + 32768 + 307712, NUM_F0, 384, DIM, 384);
}

// Round 18
// 3037.627 us; speedup vs baseline: 369.3202x; 1.4131x over previous
//
#include <hip/hip_runtime.h>
#include <hip/hip_bf16.h>
#include <math.h>

#define D_P 128
#define D_T 256
#define D_F 384
#define DIM 768
#define NUM_TIMES 601
#define NUM_F0 360
#define NHEAD 12
#define HD 64
#define NLAYERS 6
#define DFF 2048
#define CTX 1024
#define SEQ 1088
#define BATCH 8
#define ROWS (BATCH*SEQ)
#define TDIM3 (3*DIM)
#define PREDROWS 512

typedef unsigned short ushort_t;
typedef __attribute__((ext_vector_type(8))) short bfrag;
typedef __attribute__((ext_vector_type(4))) float f32x4;

// Required template symbol; also the guard-path fill kernel.
__global__ void SequenceModel_30425548325019_kernel(unsigned short* out, int n, unsigned short v) {
  int i = blockIdx.x * 256 + threadIdx.x;
  if (i < n) out[i] = v;
}

__device__ inline short f2bf(float f) {
  unsigned u = __float_as_uint(f);
  unsigned r = (u + 0x7FFFu + ((u >> 16) & 1u)) >> 16;  // RNE
  return (short)r;
}

__device__ inline void gload16(const void* g, void* l) {
  __builtin_amdgcn_global_load_lds(
      (const __attribute__((address_space(1))) unsigned*)g,
      (__attribute__((address_space(3))) unsigned*)l, 16, 0, 0);
}

// ---------------- fp32 -> bf16 bulk convert ----------------
__global__ __launch_bounds__(256) void cvt_bf16(const float* __restrict__ src,
                                                ushort_t* __restrict__ dst, int n) {
  int i = (blockIdx.x * 256 + threadIdx.x) * 4;
  if (i >= n) return;
  float4 v = *(const float4*)(src + i);
  dst[i + 0] = (ushort_t)f2bf(v.x);
  dst[i + 1] = (ushort_t)f2bf(v.y);
  dst[i + 2] = (ushort_t)f2bf(v.z);
  dst[i + 3] = (ushort_t)f2bf(v.w);
}

// ---------------- embedding: writes fp32 x and bf16 xb ----------------
__global__ __launch_bounds__(256) void embed_kernel(
    const int* __restrict__ cp, const float* __restrict__ ct,
    const int* __restrict__ cf, const float* __restrict__ part,
    const float* __restrict__ f0t, const float* __restrict__ pad,
    float* __restrict__ x, ushort_t* __restrict__ xb) {
  int idx = blockIdx.x * 256 + threadIdx.x;
  if (idx >= ROWS * DIM) return;
  int d = idx % DIM;
  int row = idx / DIM;
  int b = row / SEQ, s = row - b * SEQ;
  float v;
  if (s >= CTX) {
    v = pad[d];
  } else if (d < D_P) {
    v = part[cp[b * CTX + s] * D_P + d];
  } else if (d < D_P + D_T) {
    int j = d - D_P;
    int i2 = j >> 1;
    float wk = powf(10000.f, -(float)i2 / (float)D_T) * ((float)D_T / (float)NUM_TIMES);
    float ang = ct[b * CTX + s] * wk;
    v = (j & 1) ? cosf(ang) : sinf(ang);
  } else {
    v = f0t[cf[b * CTX + s] * D_F + (d - D_P - D_T)];
  }
  x[idx] = v;
  xb[idx] = (ushort_t)f2bf(v);
}

// ---------------- bf16 MFMA NT GEMM via global_load_lds ----------------
// A[M,K] bf16, B[N,K] bf16. Epilogue: +bias (+resid fp32) (relu) (qscale cols<DIM)
// writes C fp32 (if C) and/or Cb bf16 (if Cb).
#define BM 128
#define BN 128
#define BK 32

__global__ __launch_bounds__(256) void gemm_bb(
    const ushort_t* __restrict__ A, const ushort_t* __restrict__ B,
    const float* __restrict__ bias, const float* __restrict__ resid,
    float* __restrict__ C, ushort_t* __restrict__ Cb,
    int M, int N, int K, int relu, int qscale) {
  __shared__ short As[4 * BM * 8];
  __shared__ short Bs[4 * BN * 8];
  const int tid = threadIdx.x;
  const int wave = tid >> 6, lane = tid & 63;
  const int wr = wave >> 1, wc = wave & 1;
  const int l15 = lane & 15, l4 = lane >> 4;
  const int m0 = blockIdx.y * BM, n0 = blockIdx.x * BN;
  f32x4 acc[4][4] = {};

  for (int k0 = 0; k0 < K; k0 += BK) {
    __syncthreads();
    #pragma unroll
    for (int i = 0; i < 2; ++i) {
      int u = i * 256 + wave * 64 + lane;
      int row = u & 127, kg = u >> 7;
      gload16(A + (size_t)(m0 + row) * K + k0 + kg * 8, &As[(i * 256 + wave * 64) * 8]);
      gload16(B + (size_t)(n0 + row) * K + k0 + kg * 8, &Bs[(i * 256 + wave * 64) * 8]);
    }
    __syncthreads();
    bfrag a[4], b[4];
    #pragma unroll
    for (int f = 0; f < 4; ++f) {
      a[f] = *(const bfrag*)&As[(l4 * BM + wr * 64 + f * 16 + l15) * 8];
      b[f] = *(const bfrag*)&Bs[(l4 * BN + wc * 64 + f * 16 + l15) * 8];
    }
    #pragma unroll
    for (int i = 0; i < 4; ++i)
      #pragma unroll
      for (int j = 0; j < 4; ++j)
        acc[i][j] = __builtin_amdgcn_mfma_f32_16x16x32_bf16(a[i], b[j], acc[i][j], 0, 0, 0);
  }
  #pragma unroll
  for (int i = 0; i < 4; ++i) {
    int mbase = m0 + wr * 64 + i * 16 + l4 * 4;
    #pragma unroll
    for (int j = 0; j < 4; ++j) {
      int n = n0 + wc * 64 + j * 16 + l15;
      float bv = bias[n];
      #pragma unroll
      for (int r = 0; r < 4; ++r) {
        int m = mbase + r;
        float v = acc[i][j][r] + bv;
        if (resid) v += resid[(size_t)m * N + n];
        if (relu) v = fmaxf(v, 0.f);
        if (qscale && n < DIM) v *= 0.125f;
        if (C) C[(size_t)m * N + n] = v;
        if (Cb) Cb[(size_t)m * N + n] = (ushort_t)f2bf(v);
      }
    }
  }
}

// ---------------- gather pred rows (bf16) ----------------
__global__ __launch_bounds__(256) void gather_pred(const ushort_t* __restrict__ xb,
                                                   ushort_t* __restrict__ xpb) {
  int idx = blockIdx.x * 256 + threadIdx.x;
  if (idx >= PREDROWS * DIM) return;
  int r = idx / DIM, d = idx - r * DIM;
  int b = r >> 6, rr = r & 63;
  xpb[idx] = xb[(size_t)(b * SEQ + CTX + rr) * DIM + d];
}

// ---------------- head GEMM (bf16 operands, fp32 out, N-guarded stores) ------
__global__ __launch_bounds__(256) void head_mfma(
    const ushort_t* __restrict__ A, const ushort_t* __restrict__ B,
    float* __restrict__ C, int N, int K, int lda, int coloff) {
  __shared__ short As[4 * BM * 8];
  __shared__ short Bs[4 * BN * 8];
  const int tid = threadIdx.x;
  const int wave = tid >> 6, lane = tid & 63;
  const int wr = wave >> 1, wc = wave & 1;
  const int l15 = lane & 15, l4 = lane >> 4;
  const int m0 = blockIdx.y * BM, n0 = blockIdx.x * BN;
  f32x4 acc[4][4] = {};

  for (int k0 = 0; k0 < K; k0 += BK) {
    __syncthreads();
    #pragma unroll
    for (int i = 0; i < 2; ++i) {
      int u = i * 256 + wave * 64 + lane;
      int row = u & 127, kg = u >> 7;
      gload16(A + (size_t)(m0 + row) * lda + coloff + k0 + kg * 8,
              &As[(i * 256 + wave * 64) * 8]);
      // B rows beyond N read garbage inside d_ws; their columns are discarded.
      gload16(B + (size_t)(n0 + row) * K + k0 + kg * 8,
              &Bs[(i * 256 + wave * 64) * 8]);
    }
    __syncthreads();
    bfrag a[4], b[4];
    #pragma unroll
    for (int f = 0; f < 4; ++f) {
      a[f] = *(const bfrag*)&As[(l4 * BM + wr * 64 + f * 16 + l15) * 8];
      b[f] = *(const bfrag*)&Bs[(l4 * BN + wc * 64 + f * 16 + l15) * 8];
    }
    #pragma unroll
    for (int i = 0; i < 4; ++i)
      #pragma unroll
      for (int j = 0; j < 4; ++j)
        acc[i][j] = __builtin_amdgcn_mfma_f32_16x16x32_bf16(a[i], b[j], acc[i][j], 0, 0, 0);
  }
  #pragma unroll
  for (int i = 0; i < 4; ++i) {
    int mbase = m0 + wr * 64 + i * 16 + l4 * 4;
    #pragma unroll
    for (int j = 0; j < 4; ++j) {
      int n = n0 + wc * 64 + j * 16 + l15;
      if (n >= N) continue;
      #pragma unroll
      for (int r = 0; r < 4; ++r)
        C[(size_t)(mbase + r) * N + n] = acc[i][j][r];
    }
  }
}

// ---------------- MFMA flash attention, QBLK=64, bf16 in/out ----------------
#define QBLK 64
__global__ __launch_bounds__(256) void attn_mfma(const ushort_t* __restrict__ qkv,
                                                 ushort_t* __restrict__ outb) {
  const int qt = blockIdx.x, h = blockIdx.y, b = blockIdx.z;
  const int q0 = qt * QBLK;
  __shared__ short Qs[8 * 64 * 8];
  __shared__ short Ks[8 * 32 * 8];
  __shared__ short Vt[4 * 64 * 9];
  __shared__ short Ps[4 * 64 * 9];
  __shared__ float SO[64 * 68];
  __shared__ float alphaS[64], linvS[64];
  const int tid = threadIdx.x;
  const int wave = tid >> 6, lane = tid & 63;
  const int l15 = lane & 15, l4 = lane >> 4;
  const int srow = tid >> 3, skg = tid & 7;
  const int smrow = tid >> 2, smc = tid & 3;
  const int qf = wave;

  // stage Q (already scaled by 1/8 in QKV epilogue)
  #pragma unroll
  for (int i = 0; i < 2; ++i) {
    int s = tid + 256 * i;
    int r = s >> 3, kg = s & 7;
    const ushort_t* qp = qkv + (size_t)(b * SEQ + q0 + r) * TDIM3 + h * HD + kg * 8;
    *(bfrag*)&Qs[(kg * 64 + ((r + kg) & 63)) * 8] = *(const bfrag*)qp;
  }
  float mrun = -1e30f, lrun = 0.f;
  f32x4 o[4] = {};
  const int nkt = (q0 < CTX) ? (q0 + QBLK) / 32 : (CTX / 32);

  for (int kt = 0; kt < nkt; ++kt) {
    const int k0 = kt * 32;
    __syncthreads();
    {
      const ushort_t* kp = qkv + (size_t)(b * SEQ + k0 + srow) * TDIM3 + DIM + h * HD + skg * 8;
      *(bfrag*)&Ks[(skg * 32 + ((srow + skg) & 31)) * 8] = *(const bfrag*)kp;
      bfrag vv = *(const bfrag*)(kp + DIM);
      int kg2 = srow >> 3, j = srow & 7, db = skg * 8;
      #pragma unroll
      for (int e = 0; e < 8; ++e)
        Vt[(kg2 * 64 + db + e) * 9 + j] = vv[e];
    }
    __syncthreads();
    #pragma unroll
    for (int jk = 0; jk < 2; ++jk) {
      f32x4 s = {};
      #pragma unroll
      for (int t = 0; t < 2; ++t) {
        int kg = t * 4 + l4;
        int ar = qf * 16 + l15;
        bfrag a = *(const bfrag*)&Qs[(kg * 64 + ((ar + kg) & 63)) * 8];
        int br = jk * 16 + l15;
        bfrag bb = *(const bfrag*)&Ks[(kg * 32 + ((br + kg) & 31)) * 8];
        s = __builtin_amdgcn_mfma_f32_16x16x32_bf16(a, bb, s, 0, 0, 0);
      }
      #pragma unroll
      for (int r = 0; r < 4; ++r)
        SO[(qf * 16 + l4 * 4 + r) * 33 + jk * 16 + l15] = s[r];
    }
    __syncthreads();
    {
      const int qglob = q0 + smrow;
      float p[8];
      float tm = -1e30f;
      #pragma unroll
      for (int i = 0; i < 8; ++i) {
        int kg = k0 + smc * 8 + i;
        float s = SO[smrow * 33 + smc * 8 + i];
        bool allowed = (qglob < CTX) ? (kg <= qglob) : true;
        p[i] = allowed ? s : -1e30f;
        tm = fmaxf(tm, p[i]);
      }
      tm = fmaxf(tm, __shfl_xor(tm, 1));
      tm = fmaxf(tm, __shfl_xor(tm, 2));
      float mn = fmaxf(mrun, tm);
      float alpha = __expf(mrun - mn);
      float ls = 0.f;
      #pragma unroll
      for (int i = 0; i < 8; ++i) { p[i] = __expf(p[i] - mn); ls += p[i]; }
      ls += __shfl_xor(ls, 1);
      ls += __shfl_xor(ls, 2);
      lrun = lrun * alpha + ls;
      mrun = mn;
      if (smc == 0) alphaS[smrow] = alpha;
      short* pd = &Ps[(smc * 64 + smrow) * 9];
      #pragma unroll
      for (int i = 0; i < 8; ++i) pd[i] = f2bf(p[i]);
    }
    __syncthreads();
    {
      #pragma unroll
      for (int r = 0; r < 4; ++r) {
        float ar = alphaS[qf * 16 + l4 * 4 + r];
        #pragma unroll
        for (int df = 0; df < 4; ++df) o[df][r] *= ar;
      }
      bfrag pa = *(const bfrag*)&Ps[(l4 * 64 + qf * 16 + l15) * 9];
      #pragma unroll
      for (int df = 0; df < 4; ++df) {
        bfrag v = *(const bfrag*)&Vt[(l4 * 64 + df * 16 + l15) * 9];
        o[df] = __builtin_amdgcn_mfma_f32_16x16x32_bf16(pa, v, o[df], 0, 0, 0);
      }
    }
  }
  if (smc == 0) linvS[smrow] = 1.f / lrun;
  __syncthreads();
  #pragma unroll
  for (int r = 0; r < 4; ++r) {
    float li = linvS[qf * 16 + l4 * 4 + r];
    #pragma unroll
    for (int df = 0; df < 4; ++df)
      SO[(qf * 16 + l4 * 4 + r) * 68 + df * 16 + l15] = o[df][r] * li;
  }
  __syncthreads();
  #pragma unroll
  for (int i = 0; i < 2; ++i) {
    int s = tid + 256 * i;
    int r = s >> 3, kg = s & 7;
    ushort_t* dst = outb + (size_t)(b * SEQ + q0 + r) * DIM + h * HD + kg * 8;
    const float* sp = &SO[r * 68 + kg * 8];
    bfrag t;
    #pragma unroll
    for (int e = 0; e < 8; ++e) t[e] = f2bf(sp[e]);
    *(bfrag*)dst = t;
  }
}

// ---------------- layernorm: in-place fp32 + bf16 shadow ----------------
__global__ __launch_bounds__(256) void ln_kernel(float* __restrict__ x,
                                                 const float* __restrict__ g,
                                                 const float* __restrict__ bb,
                                                 ushort_t* __restrict__ xb) {
  const int row = blockIdx.x;
  float* p = x + (size_t)row * DIM;
  ushort_t* pb = xb + (size_t)row * DIM;
  const int tid = threadIdx.x;
  float v0 = p[tid], v1 = p[tid + 256], v2 = p[tid + 512];
  float s1 = v0 + v1 + v2;
  float s2 = v0 * v0 + v1 * v1 + v2 * v2;
  #pragma unroll
  for (int off = 32; off >= 1; off >>= 1) {
    s1 += __shfl_down(s1, off);
    s2 += __shfl_down(s2, off);
  }
  __shared__ float r1[4], r2[4];
  int wid = tid >> 6;
  if ((tid & 63) == 0) { r1[wid] = s1; r2[wid] = s2; }
  __syncthreads();
  s1 = r1[0] + r1[1] + r1[2] + r1[3];
  s2 = r2[0] + r2[1] + r2[2] + r2[3];
  const float mu = s1 * (1.f / DIM);
  const float var = s2 * (1.f / DIM) - mu * mu;
  const float rs = rsqrtf(var + 1e-5f);
  float o0 = (v0 - mu) * rs * g[tid]       + bb[tid];
  float o1 = (v1 - mu) * rs * g[tid + 256] + bb[tid + 256];
  float o2 = (v2 - mu) * rs * g[tid + 512] + bb[tid + 512];
  p[tid] = o0;       pb[tid] = (ushort_t)f2bf(o0);
  p[tid + 256] = o1; pb[tid + 256] = (ushort_t)f2bf(o1);
  p[tid + 512] = o2; pb[tid + 512] = (ushort_t)f2bf(o2);
}

extern "C" void kernel_launch(void* const* d_in, const int* in_sizes, int n_in,
                              void* d_out, int out_size, void* d_ws, size_t ws_size,
                              hipStream_t stream) {
  // ws layout (floats):
  const size_t N_X    = (size_t)ROWS * DIM;            // fp32 residual stream
  const size_t N_XB   = N_X / 2;                       // bf16 shadow
  const size_t N_BUFB = (size_t)ROWS * TDIM3 / 2;      // bf16 qkv / ff hidden
  const size_t N_CTB  = N_X / 2;                       // bf16 attn out
  const size_t N_WQ   = 10616832 / 2;
  const size_t N_WO   = 3538944 / 2;
  const size_t N_W1   = 9437184 / 2;
  const size_t N_W2   = 9437184 / 2;
  const size_t N_PT   = 8192 / 2;
  const size_t N_TT   = 153856 / 2;
  const size_t N_FT   = 138240 / 2;
  const size_t N_XPB  = (size_t)PREDROWS * DIM / 2;
  size_t need = (N_X + N_XB + N_BUFB + N_CTB + N_WQ + N_WO + N_W1 + N_W2 +
                 N_PT + N_TT + N_FT + N_XPB) * sizeof(float);
  if (ws_size < need) {
    SequenceModel_30425548325019_kernel<<<(out_size + 255) / 256, 256, 0, stream>>>(
        (unsigned short*)d_out, out_size, (unsigned short)0x4280);
    return;
  }

  const int*   cp    = (const int*)d_in[0];
  const float* ct    = (const float*)d_in[1];
  const int*   cf    = (const int*)d_in[2];
  const float* part  = (const float*)d_in[3];
  const float* timet = (const float*)d_in[4];
  const float* f0t   = (const float*)d_in[5];
  const float* pad   = (const float*)d_in[6];
  const float* Wqkv  = (const float*)d_in[7];
  const float* bqkv  = (const float*)d_in[8];
  const float* Wo    = (const float*)d_in[9];
  const float* bo    = (const float*)d_in[10];
  const float* ln1g  = (const float*)d_in[11];
  const float* ln1b  = (const float*)d_in[12];
  const float* W1    = (const float*)d_in[13];
  const float* b1    = (const float*)d_in[14];
  const float* W2    = (const float*)d_in[15];
  const float* b2    = (const float*)d_in[16];
  const float* ln2g  = (const float*)d_in[17];
  const float* ln2b  = (const float*)d_in[18];

  float* base = (float*)d_ws;
  float*    x      = base;                 base += N_X;
  ushort_t* xb     = (ushort_t*)base;      base += N_XB;
  ushort_t* bufb   = (ushort_t*)base;      base += N_BUFB;
  ushort_t* ctxbb  = (ushort_t*)base;      base += N_CTB;
  ushort_t* Wqkvb  = (ushort_t*)base;      base += N_WQ;
  ushort_t* Wob    = (ushort_t*)base;      base += N_WO;
  ushort_t* W1b    = (ushort_t*)base;      base += N_W1;
  ushort_t* W2b    = (ushort_t*)base;      base += N_W2;
  ushort_t* partb  = (ushort_t*)base;      base += N_PT;
  ushort_t* timetb = (ushort_t*)base;      base += N_TT;
  ushort_t* f0tb   = (ushort_t*)base;      base += N_FT;
  ushort_t* xpb    = (ushort_t*)base;

  // one-time weight/table conversion
  cvt_bf16<<<(10616832 / 4 + 255) / 256, 256, 0, stream>>>(Wqkv, Wqkvb, 10616832);
  cvt_bf16<<<(3538944 / 4 + 255) / 256, 256, 0, stream>>>(Wo, Wob, 3538944);
  cvt_bf16<<<(9437184 / 4 + 255) / 256, 256, 0, stream>>>(W1, W1b, 9437184);
  cvt_bf16<<<(9437184 / 4 + 255) / 256, 256, 0, stream>>>(W2, W2b, 9437184);
  cvt_bf16<<<(8192 / 4 + 255) / 256, 256, 0, stream>>>(part, partb, 8192);
  cvt_bf16<<<(153856 / 4 + 255) / 256, 256, 0, stream>>>(timet, timetb, 153856);
  cvt_bf16<<<(138240 / 4 + 255) / 256, 256, 0, stream>>>(f0t, f0tb, 138240);

  embed_kernel<<<(ROWS * DIM + 255) / 256, 256, 0, stream>>>(cp, ct, cf, part, f0t, pad, x, xb);

  for (int l = 0; l < NLAYERS; ++l) {
    // QKV (bf16 out, Q pre-scaled by 1/8)
    gemm_bb<<<dim3(TDIM3 / BN, ROWS / BM), 256, 0, stream>>>(
        xb, Wqkvb + (size_t)l * TDIM3 * DIM, bqkv + l * TDIM3, nullptr,
        nullptr, bufb, ROWS, TDIM3, DIM, 0, 1);
    attn_mfma<<<dim3(SEQ / QBLK, NHEAD, BATCH), 256, 0, stream>>>(bufb, ctxbb);
    // Wo: resid=x, in-place C=x
    gemm_bb<<<dim3(DIM / BN, ROWS / BM), 256, 0, stream>>>(
        ctxbb, Wob + (size_t)l * DIM * DIM, bo + l * DIM, x,
        x, nullptr, ROWS, DIM, DIM, 0, 0);
    ln_kernel<<<ROWS, 256, 0, stream>>>(x, ln1g + l * DIM, ln1b + l * DIM, xb);
    // W1 (relu, bf16 out)
    gemm_bb<<<dim3(DFF / BN, ROWS / BM), 256, 0, stream>>>(
        xb, W1b + (size_t)l * DFF * DIM, b1 + l * DFF, nullptr,
        nullptr, bufb, ROWS, DFF, DIM, 1, 0);
    // W2: resid=x, in-place C=x
    gemm_bb<<<dim3(DIM / BN, ROWS / BM), 256, 0, stream>>>(
        bufb, W2b + (size_t)l * DIM * DFF, b2 + l * DIM, x,
        x, nullptr, ROWS, DIM, DFF, 0, 0);
    ln_kernel<<<ROWS, 256, 0, stream>>>(x, ln2g + l * DIM, ln2b + l * DIM, xb);
  }

  float* out = (float*)d_out;
  gather_pred<<<(PREDROWS * DIM + 255) / 256, 256, 0, stream>>>(xb, xpb);
  head_mfma<<<dim3(1, PREDROWS / BM), 256, 0, stream>>>(xpb, partb, out, 64, 128, DIM, 0);
  head_mfma<<<dim3(5, PREDROWS / BM), 256, 0, stream>>>(xpb, timetb, out + 32768, NUM_TIMES, 256, DIM, 128);
  head_mfma<<<dim3(3, PREDROWS / BM), 256, 0, stream>>>(xpb, f0tb, out + 32768 + 307712, NUM_F0, 384, DIM, 384);
}